// Round 1
// baseline (1369.447 us; speedup 1.0000x reference)
//
#include <hip/hip_runtime.h>
#include <math.h>

#define HH    512
#define DIN   512
#define NHT   2051
#define PRE_LD 2052
#define DICT  8192
#define BATCH 4096
#define NCYC  10
#define DTT   0.6f
#define EPSV  1e-8f

#define KC   16
#define LDSP 68   // k-major LDS row stride (floats); 68*4B=272B, 16B-aligned, 2-way max conflict

__device__ __forceinline__ float sigmoidf_(float x) { return 1.0f / (1.0f + __expf(-x)); }

__device__ __forceinline__ float waveReduceSum(float v) {
#pragma unroll
  for (int o = 1; o < 64; o <<= 1) v += __shfl_xor(v, o);
  return v;
}

// ---------------- GEMM tile accumulators ----------------
// C[m,n] += sum_k A[m,k] * B[n,k]   (NT: both K-contiguous)
__device__ __forceinline__ void gemm_accum_nt(
    const float* __restrict__ A, int lda,
    const float* __restrict__ Bm, int ldb, int nvalid,
    int m0, int n0, int K,
    float (&acc)[4][4], float* As, float* Bs, int tid)
{
  const int lrow = tid >> 2;
  const int lk4  = (tid & 3) << 2;
  const int tx = tid & 15, ty = tid >> 4;
  for (int k0 = 0; k0 < K; k0 += KC) {
    float4 a = *(const float4*)(A + (size_t)(m0 + lrow) * lda + k0 + lk4);
    float4 b = make_float4(0.f, 0.f, 0.f, 0.f);
    if (lrow < nvalid)
      b = *(const float4*)(Bm + (size_t)(n0 + lrow) * ldb + k0 + lk4);
    __syncthreads();
    As[(lk4 + 0) * LDSP + lrow] = a.x;
    As[(lk4 + 1) * LDSP + lrow] = a.y;
    As[(lk4 + 2) * LDSP + lrow] = a.z;
    As[(lk4 + 3) * LDSP + lrow] = a.w;
    Bs[(lk4 + 0) * LDSP + lrow] = b.x;
    Bs[(lk4 + 1) * LDSP + lrow] = b.y;
    Bs[(lk4 + 2) * LDSP + lrow] = b.z;
    Bs[(lk4 + 3) * LDSP + lrow] = b.w;
    __syncthreads();
#pragma unroll
    for (int k = 0; k < KC; ++k) {
      float4 a4 = *(const float4*)(As + k * LDSP + (ty << 2));
      float4 b4 = *(const float4*)(Bs + k * LDSP + (tx << 2));
      float av[4] = {a4.x, a4.y, a4.z, a4.w};
      float bv[4] = {b4.x, b4.y, b4.z, b4.w};
#pragma unroll
      for (int i = 0; i < 4; ++i)
#pragma unroll
        for (int j = 0; j < 4; ++j)
          acc[i][j] = fmaf(av[i], bv[j], acc[i][j]);
    }
  }
}

// C[m,n] += sum_k A[m,k] * B[k,n]   (NN: B is K-major already)
__device__ __forceinline__ void gemm_accum_nn(
    const float* __restrict__ A, int lda,
    const float* __restrict__ Bm, int ldb,
    int m0, int n0, int K,
    float (&acc)[4][4], float* As, float* Bs, int tid)
{
  const int arow = tid >> 2;
  const int ak4  = (tid & 3) << 2;
  const int bk   = tid >> 4;
  const int bn4  = (tid & 15) << 2;
  const int tx = tid & 15, ty = tid >> 4;
  for (int k0 = 0; k0 < K; k0 += KC) {
    float4 a = *(const float4*)(A + (size_t)(m0 + arow) * lda + k0 + ak4);
    float4 b = *(const float4*)(Bm + (size_t)(k0 + bk) * ldb + n0 + bn4);
    __syncthreads();
    As[(ak4 + 0) * LDSP + arow] = a.x;
    As[(ak4 + 1) * LDSP + arow] = a.y;
    As[(ak4 + 2) * LDSP + arow] = a.z;
    As[(ak4 + 3) * LDSP + arow] = a.w;
    *(float4*)(Bs + bk * LDSP + bn4) = b;
    __syncthreads();
#pragma unroll
    for (int k = 0; k < KC; ++k) {
      float4 a4 = *(const float4*)(As + k * LDSP + (ty << 2));
      float4 b4 = *(const float4*)(Bs + k * LDSP + (tx << 2));
      float av[4] = {a4.x, a4.y, a4.z, a4.w};
      float bv[4] = {b4.x, b4.y, b4.z, b4.w};
#pragma unroll
      for (int i = 0; i < 4; ++i)
#pragma unroll
        for (int j = 0; j < 4; ++j)
          acc[i][j] = fmaf(av[i], bv[j], acc[i][j]);
    }
  }
}

// ---------------- kernels ----------------
__global__ __launch_bounds__(256) void k_preact(
    const float* __restrict__ x, const float* __restrict__ h,
    const float* __restrict__ Wi, const float* __restrict__ Wh,
    const float* __restrict__ bi, const float* __restrict__ bh,
    float* __restrict__ pre)
{
  __shared__ float As[KC * LDSP];
  __shared__ float Bs[KC * LDSP];
  const int tid = threadIdx.x;
  const int m0 = blockIdx.y << 6, n0 = blockIdx.x << 6;
  int nvalid = NHT - n0; if (nvalid > 64) nvalid = 64;
  float acc[4][4] = {};
  gemm_accum_nt(x, DIN, Wi, DIN, nvalid, m0, n0, DIN, acc, As, Bs, tid);
  gemm_accum_nt(h, HH,  Wh, HH,  nvalid, m0, n0, HH,  acc, As, Bs, tid);
  const int tx = tid & 15, ty = tid >> 4;
#pragma unroll
  for (int i = 0; i < 4; ++i)
#pragma unroll
    for (int j = 0; j < 4; ++j) {
      int n = n0 + (tx << 2) + j;
      if (n < NHT) {
        int m = m0 + (ty << 2) + i;
        pre[(size_t)m * PRE_LD + n] = acc[i][j] + bi[n] + bh[n];
      }
    }
}

__global__ __launch_bounds__(256) void k_gates(
    const float* __restrict__ pre, const float* __restrict__ c_prev,
    float* __restrict__ ct, float* __restrict__ ot,
    float* __restrict__ inps, float* __restrict__ leak,
    float* __restrict__ comp, float* __restrict__ qn)
{
  const int b = blockIdx.x, t = threadIdx.x;
  const float* row = pre + (size_t)b * PRE_LD;
  float ss = 0.f;
#pragma unroll
  for (int j = t; j < HH; j += 256) {
    float f  = sigmoidf_(row[j]);
    float o  = sigmoidf_(row[HH + j]);
    float ii = sigmoidf_(row[2 * HH + j]);
    float cn = tanhf(row[3 * HH + 3 + j]);
    float c  = c_prev[(size_t)b * HH + j] * f + ii * cn;
    ct[(size_t)b * HH + j] = c;
    ot[(size_t)b * HH + j] = o;
    ss += c * c;
  }
  ss = waveReduceSum(ss);
  __shared__ float ps[4];
  if ((t & 63) == 0) ps[t >> 6] = ss;
  __syncthreads();
  if (t == 0) {
    qn[b]   = sqrtf(ps[0] + ps[1] + ps[2] + ps[3]);
    inps[b] = sigmoidf_(row[3 * HH + 0]);
    leak[b] = sigmoidf_(row[3 * HH + 1]);
    comp[b] = sigmoidf_(row[3 * HH + 2]);
  }
}

__global__ __launch_bounds__(256) void k_mn(const float* __restrict__ vals, float* __restrict__ mn)
{
  const int row  = blockIdx.x * 4 + (threadIdx.x >> 6);
  const int lane = threadIdx.x & 63;
  const float* v = vals + (size_t)row * HH;
  float ss = 0.f;
#pragma unroll
  for (int j = lane; j < HH; j += 64) { float x = v[j]; ss += x * x; }
  ss = waveReduceSum(ss);
  if (lane == 0) mn[row] = sqrtf(ss);
}

__global__ __launch_bounds__(256) void k_copyvals(const float* __restrict__ vals, float* __restrict__ nv)
{
  size_t i = (size_t)blockIdx.x * blockDim.x + threadIdx.x;
  ((float4*)nv)[i] = ((const float4*)vals)[i];
}

__global__ __launch_bounds__(256) void k_sim(
    const float* __restrict__ ct, const float* __restrict__ vals,
    const float* __restrict__ qn, const float* __restrict__ mn,
    float* __restrict__ sim)
{
  __shared__ float As[KC * LDSP];
  __shared__ float Bs[KC * LDSP];
  const int tid = threadIdx.x;
  const int m0 = blockIdx.y << 6, n0 = blockIdx.x << 6;
  float acc[4][4] = {};
  gemm_accum_nt(ct, HH, vals, HH, 64, m0, n0, HH, acc, As, Bs, tid);
  const int tx = tid & 15, ty = tid >> 4;
#pragma unroll
  for (int i = 0; i < 4; ++i)
#pragma unroll
    for (int j = 0; j < 4; ++j) {
      int m = m0 + (ty << 2) + i, n = n0 + (tx << 2) + j;
      sim[(size_t)m * DICT + n] = acc[i][j] / fmaxf(qn[m] * mn[n], EPSV);
    }
}

__global__ __launch_bounds__(256) void k_lca(
    float* __restrict__ sim, const float* __restrict__ inps,
    const float* __restrict__ leak, const float* __restrict__ comp)
{
  const int b = blockIdx.x, t = threadIdx.x;
  float* srow = sim + (size_t)b * DICT;
  const float ffs = DTT * inps[b];
  const float a   = 1.0f - DTT * leak[b] + DTT * comp[b];
  const float cdt = DTT * comp[b];
  float ff[32], V[32];
#pragma unroll
  for (int i = 0; i < 32; ++i) { ff[i] = ffs * srow[t + i * 256]; V[i] = 0.f; }
  __shared__ float ps[4];
  for (int it = 0; it < NCYC; ++it) {
    float s = 0.f;
#pragma unroll
    for (int i = 0; i < 32; ++i) s += V[i];
    s = waveReduceSum(s);
    if ((t & 63) == 0) ps[t >> 6] = s;
    __syncthreads();
    float S = ps[0] + ps[1] + ps[2] + ps[3];
    __syncthreads();
    float sub = cdt * S;
#pragma unroll
    for (int i = 0; i < 32; ++i) V[i] = fmaxf(fmaf(a, V[i], ff[i] - sub), 0.f);
  }
#pragma unroll
  for (int i = 0; i < 32; ++i) srow[t + i * 256] = V[i];
}

__global__ __launch_bounds__(256) void k_mt(
    const float* __restrict__ w, const float* __restrict__ vals,
    const float* __restrict__ ct, const float* __restrict__ ot,
    const int* __restrict__ mptr,
    float* __restrict__ out_mt, float* __restrict__ out_cmt,
    float* __restrict__ out_ht, float* __restrict__ out_nv)
{
  __shared__ float As[KC * LDSP];
  __shared__ float Bs[KC * LDSP];
  const int tid = threadIdx.x;
  const int m0 = blockIdx.y << 6, n0 = blockIdx.x << 6;
  float acc[4][4] = {};
  gemm_accum_nn(w, DICT, vals, HH, m0, n0, DICT, acc, As, Bs, tid);
  const int tx = tid & 15, ty = tid >> 4;
  const int mp = mptr[0];
#pragma unroll
  for (int i = 0; i < 4; ++i)
#pragma unroll
    for (int j = 0; j < 4; ++j) {
      int m = m0 + (ty << 2) + i, n = n0 + (tx << 2) + j;
      size_t off = (size_t)m * HH + n;
      float mt = acc[i][j];
      float cm = ct[off] + mt;
      float ht = ot[off] * tanhf(cm);
      out_mt[off]  = mt;
      out_cmt[off] = cm;
      out_ht[off]  = ht;
      out_nv[(size_t)((mp + m) & (DICT - 1)) * HH + n] = cm;
    }
}

__global__ __launch_bounds__(256) void k_a2c(
    const float* __restrict__ ht, const float* __restrict__ Wih,
    const float* __restrict__ bih, float* __restrict__ a2c)
{
  __shared__ float As[KC * LDSP];
  __shared__ float Bs[KC * LDSP];
  const int tid = threadIdx.x;
  const int m0 = blockIdx.y << 6, n0 = blockIdx.x << 6;
  float acc[4][4] = {};
  gemm_accum_nt(ht, HH, Wih, HH, 64, m0, n0, HH, acc, As, Bs, tid);
  const int tx = tid & 15, ty = tid >> 4;
#pragma unroll
  for (int i = 0; i < 4; ++i)
#pragma unroll
    for (int j = 0; j < 4; ++j) {
      int m = m0 + (ty << 2) + i, n = n0 + (tx << 2) + j;
      a2c[(size_t)m * HH + n] = fmaxf(acc[i][j] + bih[n], 0.f);
    }
}

__global__ __launch_bounds__(256) void k_actor(
    const float* __restrict__ a2c,
    const float* __restrict__ Wact, const float* __restrict__ bact,
    const float* __restrict__ Wcr,  const float* __restrict__ bcr,
    float* __restrict__ out_pi, float* __restrict__ out_val)
{
  const int b    = blockIdx.x * 4 + (threadIdx.x >> 6);
  const int lane = threadIdx.x & 63;
  const float* hrow = a2c + (size_t)b * HH;
  float4 a0 = *(const float4*)(hrow + (lane << 3));
  float4 a1 = *(const float4*)(hrow + (lane << 3) + 4);
  float lg[17];
#pragma unroll
  for (int o = 0; o < 17; ++o) {
    const float* wr = (o < 16) ? (Wact + (size_t)o * HH) : Wcr;
    float4 w0 = *(const float4*)(wr + (lane << 3));
    float4 w1 = *(const float4*)(wr + (lane << 3) + 4);
    float s = a0.x * w0.x + a0.y * w0.y + a0.z * w0.z + a0.w * w0.w
            + a1.x * w1.x + a1.y * w1.y + a1.z * w1.z + a1.w * w1.w;
    lg[o] = waveReduceSum(s);
  }
#pragma unroll
  for (int o = 0; o < 16; ++o) lg[o] += bact[o];
  float mx = lg[0];
#pragma unroll
  for (int o = 1; o < 16; ++o) mx = fmaxf(mx, lg[o]);
  float e[16], sum = 0.f;
#pragma unroll
  for (int o = 0; o < 16; ++o) { e[o] = __expf(lg[o] - mx); sum += e[o]; }
  float rs = 1.f / sum;
  if (lane == 0) {
#pragma unroll
    for (int o = 0; o < 16; ++o) out_pi[(size_t)b * 16 + o] = e[o] * rs;
    out_val[b] = lg[16] + bcr[0];
  }
}

// ---------------- launch ----------------
extern "C" void kernel_launch(void* const* d_in, const int* in_sizes, int n_in,
                              void* d_out, int out_size, void* d_ws, size_t ws_size,
                              hipStream_t stream)
{
  const float* x    = (const float*)d_in[0];
  const float* h    = (const float*)d_in[1];
  const float* c    = (const float*)d_in[2];
  const float* Wi   = (const float*)d_in[3];
  const float* bi   = (const float*)d_in[4];
  const float* Wh   = (const float*)d_in[5];
  const float* bh   = (const float*)d_in[6];
  const float* vals = (const float*)d_in[7];
  const float* Wih  = (const float*)d_in[8];
  const float* bih  = (const float*)d_in[9];
  const float* Wact = (const float*)d_in[10];
  const float* bact = (const float*)d_in[11];
  const float* Wcr  = (const float*)d_in[12];
  const float* bcr  = (const float*)d_in[13];
  const int*   mptr = (const int*)d_in[14];

  float* ws   = (float*)d_ws;
  float* pre  = ws;                          // 4096*2052 = 8,404,992
  float* ct   = ws + 8404992;                // 2,097,152
  float* ot   = ct + 2097152;                // 2,097,152
  float* inps = ot + 2097152;
  float* leak = inps + 4096;
  float* comp = leak + 4096;
  float* qn   = comp + 4096;
  float* mn   = qn + 4096;                   // 8192
  float* sim  = mn + 8192;                   // 33,554,432
  float* a2c  = pre;                         // reuse preact region

  float* out      = (float*)d_out;
  float* out_pi   = out;
  float* out_val  = out + 65536;
  float* out_ht   = out + 69632;
  float* out_cmt  = out_ht + 2097152;
  float* out_mt   = out_cmt + 2097152;
  float* out_nv   = out_mt + 2097152;

  dim3 b256(256);
  k_preact  <<<dim3(33, 64),  b256, 0, stream>>>(x, h, Wi, Wh, bi, bh, pre);
  k_gates   <<<dim3(BATCH),   b256, 0, stream>>>(pre, c, ct, ot, inps, leak, comp, qn);
  k_mn      <<<dim3(DICT/4),  b256, 0, stream>>>(vals, mn);
  k_copyvals<<<dim3(4096),    b256, 0, stream>>>(vals, out_nv);
  k_sim     <<<dim3(128, 64), b256, 0, stream>>>(ct, vals, qn, mn, sim);
  k_lca     <<<dim3(BATCH),   b256, 0, stream>>>(sim, inps, leak, comp);
  k_mt      <<<dim3(8, 64),   b256, 0, stream>>>(sim, vals, ct, ot, mptr, out_mt, out_cmt, out_ht, out_nv);
  k_a2c     <<<dim3(8, 64),   b256, 0, stream>>>(out_ht, Wih, bih, a2c);
  k_actor   <<<dim3(BATCH/4), b256, 0, stream>>>(a2c, Wact, bact, Wcr, bcr, out_pi, out_val);
}

// Round 2
// 298.233 us; speedup vs baseline: 4.5919x; 4.5919x over previous
//
#include <hip/hip_runtime.h>
#include <hip/hip_fp16.h>
#include <math.h>

#define HH    512
#define NHT   2051
#define PRE_LD 2176
#define DICT  8192
#define BATCH 4096
#define NCYC  10
#define DTT   0.6f

#define BM  128
#define BKT 64    // K elements per tile; row = 128 bytes = 8 chunks of 16B

using f16x8 = __attribute__((ext_vector_type(8))) _Float16;
using f32x4 = __attribute__((ext_vector_type(4))) float;

__device__ __forceinline__ float sigmoidf_(float x) { return 1.0f / (1.0f + __expf(-x)); }

__device__ __forceinline__ float waveReduceSum(float v) {
#pragma unroll
  for (int o = 1; o < 64; o <<= 1) v += __shfl_xor(v, o);
  return v;
}

__device__ __forceinline__ void gld16(const void* g, void* l) {
  __builtin_amdgcn_global_load_lds(
      (const __attribute__((address_space(1))) void*)g,
      (__attribute__((address_space(3))) void*)l, 16, 0, 0);
}

// Stage ROWS x 64 f16 tile. LDS linear (global_load_lds rule), source pre-swizzled:
// data chunk k4 of row r lands in LDS slot (k4 ^ (r&7)).
template<int ROWS>
__device__ __forceinline__ void stage_tile(const __half* gbase, int ld, char* lds, int tid) {
  constexpr int ISS = ROWS * 8 / 256;
#pragma unroll
  for (int i = 0; i < ISS; ++i) {
    int cidx = i * 256 + tid;
    int row  = cidx >> 3;
    int slot = cidx & 7;
    int k4   = slot ^ (row & 7);
    gld16(gbase + (size_t)row * ld + k4 * 8, lds + cidx * 16);
  }
}

__device__ __forceinline__ f16x8 frag_ld(const char* lds, int row, int kchunk) {
  int slot = kchunk ^ (row & 7);
  return *(const f16x8*)(lds + row * 128 + slot * 16);
}

template<int FN>
__device__ __forceinline__ void tile_mfma(const char* As, const char* Bs,
                                          int lane, int wr, int wc, f32x4 (&acc)[4][FN]) {
  const int g = lane >> 4, r = lane & 15;
#pragma unroll
  for (int ks = 0; ks < 2; ++ks) {
    f16x8 af[4], bfr[FN];
#pragma unroll
    for (int i = 0; i < 4; ++i)
      af[i] = frag_ld(As, wr * 64 + i * 16 + r, ks * 4 + g);
#pragma unroll
    for (int j = 0; j < FN; ++j)
      bfr[j] = frag_ld(Bs, wc * (FN * 16) + j * 16 + r, ks * 4 + g);
#pragma unroll
    for (int i = 0; i < 4; ++i)
#pragma unroll
      for (int j = 0; j < FN; ++j)
        acc[i][j] = __builtin_amdgcn_mfma_f32_16x16x32_f16(af[i], bfr[j], acc[i][j], 0, 0, 0);
  }
}

// C[m,n] += sum_k A[m,k]*B[n,k], both f16 k-contiguous (NT). 2-phase dbuf prefetch.
template<int BN, int FN>
__device__ __forceinline__ void gemm_seg(const __half* A, int lda, const __half* B, int ldb,
                                         int m0, int n0, int K, char* lds, int tid,
                                         f32x4 (&acc)[4][FN]) {
  constexpr int ABYTES = BM * BKT * 2;
  constexpr int BBYTES = BN * BKT * 2;
  const int lane = tid & 63, wid = tid >> 6;
  const int wr = wid >> 1, wc = wid & 1;
  const int nt = K / BKT;
  const __half* Ab = A + (size_t)m0 * lda;
  const __half* Bb = B + (size_t)n0 * ldb;
  stage_tile<BM>(Ab, lda, lds, tid);
  stage_tile<BN>(Bb, ldb, lds + ABYTES, tid);
  __syncthreads();
  int cur = 0;
  for (int t = 0; t < nt - 1; ++t) {
    char* nxt = lds + (cur ^ 1) * (ABYTES + BBYTES);
    stage_tile<BM>(Ab + (t + 1) * BKT, lda, nxt, tid);
    stage_tile<BN>(Bb + (t + 1) * BKT, ldb, nxt + ABYTES, tid);
    char* curb = lds + cur * (ABYTES + BBYTES);
    tile_mfma<FN>(curb, curb + ABYTES, lane, wr, wc, acc);
    __syncthreads();   // drains vmcnt+lgkmcnt: next tile landed, cur reads done
    cur ^= 1;
  }
  char* curb = lds + cur * (ABYTES + BBYTES);
  tile_mfma<FN>(curb, curb + ABYTES, lane, wr, wc, acc);
  __syncthreads();
}

__device__ __forceinline__ void zero_acc4(f32x4 (&a)[4][4]) {
  f32x4 z = {0.f, 0.f, 0.f, 0.f};
#pragma unroll
  for (int i = 0; i < 4; ++i)
#pragma unroll
    for (int j = 0; j < 4; ++j) a[i][j] = z;
}
__device__ __forceinline__ void zero_acc2(f32x4 (&a)[4][2]) {
  f32x4 z = {0.f, 0.f, 0.f, 0.f};
#pragma unroll
  for (int i = 0; i < 4; ++i)
#pragma unroll
    for (int j = 0; j < 2; ++j) a[i][j] = z;
}

// ---------------- prep kernels ----------------
__global__ __launch_bounds__(256) void k_cvt(const float* __restrict__ in, __half* __restrict__ out,
                                             int n_in, int n_out) {
  int i = (blockIdx.x * 256 + threadIdx.x) * 4;
  if (i >= n_out) return;
  float4 v;
  if (i + 3 < n_in) v = *(const float4*)(in + i);
  else v = make_float4(i + 0 < n_in ? in[i + 0] : 0.f, i + 1 < n_in ? in[i + 1] : 0.f,
                       i + 2 < n_in ? in[i + 2] : 0.f, i + 3 < n_in ? in[i + 3] : 0.f);
  *(__half2*)(out + i)     = __floats2half2_rn(v.x, v.y);
  *(__half2*)(out + i + 2) = __floats2half2_rn(v.z, v.w);
}

__global__ __launch_bounds__(256) void k_tr(const float* __restrict__ vals, __half* __restrict__ vT) {
  __shared__ float tile[32][33];
  int r0 = blockIdx.x * 32, c0 = blockIdx.y * 32;
  int tr = threadIdx.x >> 5, tc = threadIdx.x & 31;
#pragma unroll
  for (int p = 0; p < 4; ++p)
    tile[tr + p * 8][tc] = vals[(size_t)(r0 + tr + p * 8) * HH + c0 + tc];
  __syncthreads();
#pragma unroll
  for (int p = 0; p < 4; ++p)
    vT[(size_t)(c0 + tr + p * 8) * DICT + r0 + tc] = __float2half(tile[tc][tr + p * 8]);
}

__global__ __launch_bounds__(256) void k_mn(const float* __restrict__ vals, float* __restrict__ rmn) {
  const int row = blockIdx.x * 4 + (threadIdx.x >> 6);
  const int lane = threadIdx.x & 63;
  const float* v = vals + (size_t)row * HH;
  float ss = 0.f;
#pragma unroll
  for (int j = lane; j < HH; j += 64) { float x = v[j]; ss += x * x; }
  ss = waveReduceSum(ss);
  if (lane == 0) rmn[row] = 1.f / fmaxf(sqrtf(ss), 1e-12f);
}

__global__ __launch_bounds__(256) void k_copyvals(const float* __restrict__ vals, float* __restrict__ nv) {
  size_t i = (size_t)blockIdx.x * blockDim.x + threadIdx.x;
  ((float4*)nv)[i] = ((const float4*)vals)[i];
}

// ---------------- main kernels ----------------
__global__ __launch_bounds__(256) void k_preact(
    const __half* __restrict__ x_h, const __half* __restrict__ h_h,
    const __half* __restrict__ Wi_h, const __half* __restrict__ Wh_h,
    const float* __restrict__ bi, const float* __restrict__ bh, float* __restrict__ pre) {
  __shared__ char smem[2 * (BM * BKT * 2 + 128 * BKT * 2)] __attribute__((aligned(16)));
  const int tid = threadIdx.x;
  const int m0 = blockIdx.y * 128, n0 = blockIdx.x * 128;
  f32x4 acc[4][4]; zero_acc4(acc);
  gemm_seg<128, 4>(x_h, HH, Wi_h, HH, m0, n0, HH, smem, tid, acc);
  gemm_seg<128, 4>(h_h, HH, Wh_h, HH, m0, n0, HH, smem, tid, acc);
  const int lane = tid & 63, wid = tid >> 6, wr = wid >> 1, wc = wid & 1;
#pragma unroll
  for (int fi = 0; fi < 4; ++fi)
#pragma unroll
    for (int fj = 0; fj < 4; ++fj)
#pragma unroll
      for (int q = 0; q < 4; ++q) {
        int n = n0 + wc * 64 + fj * 16 + (lane & 15);
        if (n < NHT) {
          int m = m0 + wr * 64 + fi * 16 + (lane >> 4) * 4 + q;
          pre[(size_t)m * PRE_LD + n] = acc[fi][fj][q] + bi[n] + bh[n];
        }
      }
}

__global__ __launch_bounds__(256) void k_gates(
    const float* __restrict__ pre, const float* __restrict__ c_prev,
    const float* __restrict__ x, const float* __restrict__ h,
    const float* __restrict__ Wi, const float* __restrict__ Wh,
    const float* __restrict__ bi, const float* __restrict__ bh,
    float* __restrict__ ct, float* __restrict__ ot, __half* __restrict__ ct_h,
    float* __restrict__ inps, float* __restrict__ leak,
    float* __restrict__ comp, float* __restrict__ rqn) {
  const int b = blockIdx.x, t = threadIdx.x;
  const float* row = pre + (size_t)b * PRE_LD;
  float ss = 0.f;
#pragma unroll
  for (int j = t; j < HH; j += 256) {
    float f  = sigmoidf_(row[j]);
    float o  = sigmoidf_(row[HH + j]);
    float ii = sigmoidf_(row[2 * HH + j]);
    float cn = tanhf(row[3 * HH + 3 + j]);
    float c  = c_prev[(size_t)b * HH + j] * f + ii * cn;
    size_t off = (size_t)b * HH + j;
    ct[off] = c; ot[off] = o; ct_h[off] = __float2half(c);
    ss += c * c;
  }
  ss = waveReduceSum(ss);
  __shared__ float ps[4];
  if ((t & 63) == 0) ps[t >> 6] = ss;
  // exact fp32 LCA scalar gates (cols 1536..1538)
  const int wid = t >> 6, lane = t & 63;
  float sg = 0.f;
  if (wid < 3) {
    const float* wi = Wi + (size_t)(3 * HH + wid) * HH;
    const float* wh = Wh + (size_t)(3 * HH + wid) * HH;
#pragma unroll
    for (int j = lane; j < HH; j += 64)
      sg += x[(size_t)b * HH + j] * wi[j] + h[(size_t)b * HH + j] * wh[j];
    sg = waveReduceSum(sg);
  }
  __syncthreads();
  if (t == 0) rqn[b] = 1.f / fmaxf(sqrtf(ps[0] + ps[1] + ps[2] + ps[3]), 1e-12f);
  if (wid < 3 && lane == 0) {
    float v = sigmoidf_(sg + bi[3 * HH + wid] + bh[3 * HH + wid]);
    if (wid == 0) inps[b] = v; else if (wid == 1) leak[b] = v; else comp[b] = v;
  }
}

__global__ __launch_bounds__(256) void k_sim(
    const __half* __restrict__ ct_h, const __half* __restrict__ vals_h,
    const float* __restrict__ rqn, const float* __restrict__ rmn, float* __restrict__ sim) {
  __shared__ char smem[2 * (BM * BKT * 2 + 128 * BKT * 2)] __attribute__((aligned(16)));
  const int tid = threadIdx.x;
  const int m0 = blockIdx.y * 128, n0 = blockIdx.x * 128;
  f32x4 acc[4][4]; zero_acc4(acc);
  gemm_seg<128, 4>(ct_h, HH, vals_h, HH, m0, n0, HH, smem, tid, acc);
  const int lane = tid & 63, wid = tid >> 6, wr = wid >> 1, wc = wid & 1;
#pragma unroll
  for (int fi = 0; fi < 4; ++fi)
#pragma unroll
    for (int fj = 0; fj < 4; ++fj)
#pragma unroll
      for (int q = 0; q < 4; ++q) {
        int m = m0 + wr * 64 + fi * 16 + (lane >> 4) * 4 + q;
        int n = n0 + wc * 64 + fj * 16 + (lane & 15);
        sim[(size_t)m * DICT + n] = acc[fi][fj][q] * rqn[m] * rmn[n];
      }
}

__global__ __launch_bounds__(256) void k_lca(
    const float* __restrict__ sim, const float* __restrict__ inps,
    const float* __restrict__ leak, const float* __restrict__ comp, __half* __restrict__ w_h) {
  const int b = blockIdx.x, t = threadIdx.x;
  const float* srow = sim + (size_t)b * DICT;
  const float ffs = DTT * inps[b];
  const float a   = 1.0f - DTT * leak[b] + DTT * comp[b];
  const float cdt = DTT * comp[b];
  float ff[32], V[32];
#pragma unroll
  for (int i = 0; i < 32; ++i) { ff[i] = ffs * srow[t + i * 256]; V[i] = 0.f; }
  __shared__ float ps[4];
  for (int it = 0; it < NCYC; ++it) {
    float s = 0.f;
#pragma unroll
    for (int i = 0; i < 32; ++i) s += V[i];
    s = waveReduceSum(s);
    if ((t & 63) == 0) ps[t >> 6] = s;
    __syncthreads();
    float S = ps[0] + ps[1] + ps[2] + ps[3];
    __syncthreads();
    float sub = cdt * S;
#pragma unroll
    for (int i = 0; i < 32; ++i) V[i] = fmaxf(fmaf(a, V[i], ff[i] - sub), 0.f);
  }
  __half* wrow = w_h + (size_t)b * DICT;
#pragma unroll
  for (int i = 0; i < 32; ++i) wrow[t + i * 256] = __float2half(V[i]);
}

__global__ __launch_bounds__(256) void k_mt(
    const __half* __restrict__ w_h, const __half* __restrict__ vT_h,
    const float* __restrict__ ct, const float* __restrict__ ot, const int* __restrict__ mptr,
    float* __restrict__ out_mt, float* __restrict__ out_cmt, float* __restrict__ out_ht,
    float* __restrict__ out_nv, __half* __restrict__ ht_h) {
  __shared__ char smem[2 * (BM * BKT * 2 + 64 * BKT * 2)] __attribute__((aligned(16)));
  const int tid = threadIdx.x;
  const int bid = blockIdx.x;
  const int xn = (bid >> 3) & 7, ym = (bid & 7) | ((bid >> 6) << 3);  // XCD-grouped
  const int m0 = ym * 128, n0 = xn * 64;
  f32x4 acc[4][2]; zero_acc2(acc);
  gemm_seg<64, 2>(w_h, DICT, vT_h, DICT, m0, n0, DICT, smem, tid, acc);
  const int lane = tid & 63, wid = tid >> 6, wr = wid >> 1, wc = wid & 1;
  const int mp = mptr[0];
#pragma unroll
  for (int fi = 0; fi < 4; ++fi)
#pragma unroll
    for (int fj = 0; fj < 2; ++fj)
#pragma unroll
      for (int q = 0; q < 4; ++q) {
        int m = m0 + wr * 64 + fi * 16 + (lane >> 4) * 4 + q;
        int n = n0 + wc * 32 + fj * 16 + (lane & 15);
        size_t off = (size_t)m * HH + n;
        float mt = acc[fi][fj][q];
        float cm = ct[off] + mt;
        float hv = ot[off] * tanhf(cm);
        out_mt[off] = mt; out_cmt[off] = cm; out_ht[off] = hv;
        ht_h[off] = __float2half(hv);
        out_nv[(size_t)((mp + m) & (DICT - 1)) * HH + n] = cm;
      }
}

__global__ __launch_bounds__(256) void k_a2c(
    const __half* __restrict__ ht_h, const __half* __restrict__ Wih_h,
    const float* __restrict__ bih, float* __restrict__ a2c) {
  __shared__ char smem[2 * (BM * BKT * 2 + 64 * BKT * 2)] __attribute__((aligned(16)));
  const int tid = threadIdx.x;
  const int bid = blockIdx.x;
  const int xn = (bid >> 3) & 7, ym = (bid & 7) | ((bid >> 6) << 3);
  const int m0 = ym * 128, n0 = xn * 64;
  f32x4 acc[4][2]; zero_acc2(acc);
  gemm_seg<64, 2>(ht_h, HH, Wih_h, HH, m0, n0, HH, smem, tid, acc);
  const int lane = tid & 63, wid = tid >> 6, wr = wid >> 1, wc = wid & 1;
#pragma unroll
  for (int fi = 0; fi < 4; ++fi)
#pragma unroll
    for (int fj = 0; fj < 2; ++fj)
#pragma unroll
      for (int q = 0; q < 4; ++q) {
        int m = m0 + wr * 64 + fi * 16 + (lane >> 4) * 4 + q;
        int n = n0 + wc * 32 + fj * 16 + (lane & 15);
        a2c[(size_t)m * HH + n] = fmaxf(acc[fi][fj][q] + bih[n], 0.f);
      }
}

__global__ __launch_bounds__(256) void k_actor(
    const float* __restrict__ a2c,
    const float* __restrict__ Wact, const float* __restrict__ bact,
    const float* __restrict__ Wcr, const float* __restrict__ bcr,
    float* __restrict__ out_pi, float* __restrict__ out_val) {
  const int b = blockIdx.x * 4 + (threadIdx.x >> 6);
  const int lane = threadIdx.x & 63;
  const float* hrow = a2c + (size_t)b * HH;
  float4 a0 = *(const float4*)(hrow + (lane << 3));
  float4 a1 = *(const float4*)(hrow + (lane << 3) + 4);
  float lg[17];
#pragma unroll
  for (int o = 0; o < 17; ++o) {
    const float* wr = (o < 16) ? (Wact + (size_t)o * HH) : Wcr;
    float4 w0 = *(const float4*)(wr + (lane << 3));
    float4 w1 = *(const float4*)(wr + (lane << 3) + 4);
    float s = a0.x * w0.x + a0.y * w0.y + a0.z * w0.z + a0.w * w0.w
            + a1.x * w1.x + a1.y * w1.y + a1.z * w1.z + a1.w * w1.w;
    lg[o] = waveReduceSum(s);
  }
#pragma unroll
  for (int o = 0; o < 16; ++o) lg[o] += bact[o];
  float mx = lg[0];
#pragma unroll
  for (int o = 1; o < 16; ++o) mx = fmaxf(mx, lg[o]);
  float e[16], sum = 0.f;
#pragma unroll
  for (int o = 0; o < 16; ++o) { e[o] = __expf(lg[o] - mx); sum += e[o]; }
  float rs = 1.f / sum;
  if (lane == 0) {
#pragma unroll
    for (int o = 0; o < 16; ++o) out_pi[(size_t)b * 16 + o] = e[o] * rs;
    out_val[b] = lg[16] + bcr[0];
  }
}

// ---------------- launch ----------------
extern "C" void kernel_launch(void* const* d_in, const int* in_sizes, int n_in,
                              void* d_out, int out_size, void* d_ws, size_t ws_size,
                              hipStream_t stream) {
  const float* x    = (const float*)d_in[0];
  const float* h    = (const float*)d_in[1];
  const float* c    = (const float*)d_in[2];
  const float* Wi   = (const float*)d_in[3];
  const float* bi   = (const float*)d_in[4];
  const float* Wh   = (const float*)d_in[5];
  const float* bh   = (const float*)d_in[6];
  const float* vals = (const float*)d_in[7];
  const float* Wih  = (const float*)d_in[8];
  const float* bih  = (const float*)d_in[9];
  const float* Wact = (const float*)d_in[10];
  const float* bact = (const float*)d_in[11];
  const float* Wcr  = (const float*)d_in[12];
  const float* bcr  = (const float*)d_in[13];
  const int*   mptr = (const int*)d_in[14];

  float* F = (float*)d_ws;
  // region P (16,777,216 f): pre (until k_gates), then w_h (k_lca -> k_mt)
  float*  pre    = F;
  __half* w_h    = (__half*)F;
  // region S (33,554,432 f): sim (k_sim -> k_lca), then a2c (k_a2c -> k_actor)
  float*  sim    = F + 16777216;
  float*  a2c    = sim;
  float*  ct     = F + 50331648;   // 2,097,152
  float*  ot     = F + 52428800;   // 2,097,152
  __half* ct_h   = (__half*)(F + 54525952);  // 1,048,576 f
  __half* vals_h = (__half*)(F + 55574528);  // 2,097,152 f
  __half* vT_h   = (__half*)(F + 57671680);  // 2,097,152 f
  __half* x_h    = (__half*)(F + 59768832);  // 1,048,576 f (later reused as ht_h)
  __half* ht_h   = x_h;
  __half* h_h    = (__half*)(F + 60817408);  // 1,048,576 f
  __half* Wi_h   = (__half*)(F + 61865984);  // 557,056 f (2176x512)
  __half* Wh_h   = (__half*)(F + 62423040);  // 557,056 f
  __half* Wih_h  = (__half*)(F + 62980096);  // 131,072 f
  float*  inps   = F + 63111168;
  float*  leak   = inps + 4096;
  float*  comp   = leak + 4096;
  float*  rqn    = comp + 4096;
  float*  rmn    = rqn + 4096;     // 8192

  float* out     = (float*)d_out;
  float* out_pi  = out;
  float* out_val = out + 65536;
  float* out_ht  = out + 69632;
  float* out_cmt = out_ht + 2097152;
  float* out_mt  = out_cmt + 2097152;
  float* out_nv  = out_mt + 2097152;

  dim3 b256(256);
  // converts / prep
  k_cvt<<<2048, b256, 0, stream>>>(x, x_h, 2097152, 2097152);
  k_cvt<<<2048, b256, 0, stream>>>(h, h_h, 2097152, 2097152);
  k_cvt<<<1088, b256, 0, stream>>>(Wi, Wi_h, NHT * HH, PRE_LD * HH);
  k_cvt<<<1088, b256, 0, stream>>>(Wh, Wh_h, NHT * HH, PRE_LD * HH);
  k_cvt<<<256,  b256, 0, stream>>>(Wih, Wih_h, HH * HH, HH * HH);
  k_cvt<<<4096, b256, 0, stream>>>(vals, vals_h, DICT * HH, DICT * HH);
  k_tr <<<dim3(256, 16), b256, 0, stream>>>(vals, vT_h);
  k_mn <<<DICT / 4, b256, 0, stream>>>(vals, rmn);
  k_copyvals<<<4096, b256, 0, stream>>>(vals, out_nv);
  // main pipeline
  k_preact<<<dim3(17, 32), b256, 0, stream>>>(x_h, h_h, Wi_h, Wh_h, bi, bh, pre);
  k_gates <<<BATCH, b256, 0, stream>>>(pre, c, x, h, Wi, Wh, bi, bh,
                                       ct, ot, ct_h, inps, leak, comp, rqn);
  k_sim   <<<dim3(64, 32), b256, 0, stream>>>(ct_h, vals_h, rqn, rmn, sim);
  k_lca   <<<BATCH, b256, 0, stream>>>(sim, inps, leak, comp, w_h);
  k_mt    <<<256, b256, 0, stream>>>(w_h, vT_h, ct, ot, mptr,
                                     out_mt, out_cmt, out_ht, out_nv, ht_h);
  k_a2c   <<<256, b256, 0, stream>>>(ht_h, Wih_h, bih, a2c);
  k_actor <<<BATCH / 4, b256, 0, stream>>>(a2c, Wact, bact, Wcr, bcr, out_pi, out_val);
}

// Round 3
// 258.905 us; speedup vs baseline: 5.2894x; 1.1519x over previous
//
#include <hip/hip_runtime.h>
#include <hip/hip_fp16.h>
#include <math.h>

#define HH    512
#define NHT   2051
#define PRE_LD 2176
#define DICT  8192
#define BATCH 4096
#define NCYC  10
#define DTT   0.6f

#define BM  128
#define BKT 64    // K elements per tile; row = 128 bytes = 8 chunks of 16B

using f16x8 = __attribute__((ext_vector_type(8))) _Float16;
using f32x4 = __attribute__((ext_vector_type(4))) float;

__device__ __forceinline__ float sigmoidf_(float x) { return 1.0f / (1.0f + __expf(-x)); }

__device__ __forceinline__ float waveReduceSum(float v) {
#pragma unroll
  for (int o = 1; o < 64; o <<= 1) v += __shfl_xor(v, o);
  return v;
}

__device__ __forceinline__ void gld16(const void* g, void* l) {
  __builtin_amdgcn_global_load_lds(
      (const __attribute__((address_space(1))) void*)g,
      (__attribute__((address_space(3))) void*)l, 16, 0, 0);
}

// Stage ROWS x 64 f16 tile. LDS linear (global_load_lds rule), source pre-swizzled:
// data chunk k4 of row r lands in LDS slot (k4 ^ (r&7)).
template<int ROWS>
__device__ __forceinline__ void stage_tile(const __half* gbase, int ld, char* lds, int tid) {
  constexpr int ISS = ROWS * 8 / 256;
#pragma unroll
  for (int i = 0; i < ISS; ++i) {
    int cidx = i * 256 + tid;
    int row  = cidx >> 3;
    int slot = cidx & 7;
    int k4   = slot ^ (row & 7);
    gld16(gbase + (size_t)row * ld + k4 * 8, lds + cidx * 16);
  }
}

__device__ __forceinline__ f16x8 frag_ld(const char* lds, int row, int kchunk) {
  int slot = kchunk ^ (row & 7);
  return *(const f16x8*)(lds + row * 128 + slot * 16);
}

template<int FN>
__device__ __forceinline__ void tile_mfma(const char* As, const char* Bs,
                                          int lane, int wr, int wc, f32x4 (&acc)[4][FN]) {
  const int g = lane >> 4, r = lane & 15;
#pragma unroll
  for (int ks = 0; ks < 2; ++ks) {
    f16x8 af[4], bfr[FN];
#pragma unroll
    for (int i = 0; i < 4; ++i)
      af[i] = frag_ld(As, wr * 64 + i * 16 + r, ks * 4 + g);
#pragma unroll
    for (int j = 0; j < FN; ++j)
      bfr[j] = frag_ld(Bs, wc * (FN * 16) + j * 16 + r, ks * 4 + g);
#pragma unroll
    for (int i = 0; i < 4; ++i)
#pragma unroll
      for (int j = 0; j < FN; ++j)
        acc[i][j] = __builtin_amdgcn_mfma_f32_16x16x32_f16(af[i], bfr[j], acc[i][j], 0, 0, 0);
  }
}

// C[m,n] += sum_k A[m,k]*B[n,k], both f16 k-contiguous (NT). 2-phase dbuf prefetch.
template<int BN, int FN>
__device__ __forceinline__ void gemm_seg(const __half* A, int lda, const __half* B, int ldb,
                                         int m0, int n0, int K, char* lds, int tid,
                                         f32x4 (&acc)[4][FN]) {
  constexpr int ABYTES = BM * BKT * 2;
  constexpr int BBYTES = BN * BKT * 2;
  const int lane = tid & 63, wid = tid >> 6;
  const int wr = wid >> 1, wc = wid & 1;
  const int nt = K / BKT;
  const __half* Ab = A + (size_t)m0 * lda;
  const __half* Bb = B + (size_t)n0 * ldb;
  stage_tile<BM>(Ab, lda, lds, tid);
  stage_tile<BN>(Bb, ldb, lds + ABYTES, tid);
  __syncthreads();
  int cur = 0;
  for (int t = 0; t < nt - 1; ++t) {
    char* nxt = lds + (cur ^ 1) * (ABYTES + BBYTES);
    stage_tile<BM>(Ab + (t + 1) * BKT, lda, nxt, tid);
    stage_tile<BN>(Bb + (t + 1) * BKT, ldb, nxt + ABYTES, tid);
    char* curb = lds + cur * (ABYTES + BBYTES);
    tile_mfma<FN>(curb, curb + ABYTES, lane, wr, wc, acc);
    __syncthreads();   // drains vmcnt+lgkmcnt: next tile landed, cur reads done
    cur ^= 1;
  }
  char* curb = lds + cur * (ABYTES + BBYTES);
  tile_mfma<FN>(curb, curb + ABYTES, lane, wr, wc, acc);
  __syncthreads();
}

__device__ __forceinline__ void zero_acc4(f32x4 (&a)[4][4]) {
  f32x4 z = {0.f, 0.f, 0.f, 0.f};
#pragma unroll
  for (int i = 0; i < 4; ++i)
#pragma unroll
    for (int j = 0; j < 4; ++j) a[i][j] = z;
}
__device__ __forceinline__ void zero_acc2(f32x4 (&a)[4][2]) {
  f32x4 z = {0.f, 0.f, 0.f, 0.f};
#pragma unroll
  for (int i = 0; i < 4; ++i)
#pragma unroll
    for (int j = 0; j < 2; ++j) a[i][j] = z;
}

// ---------------- fused prep kernels ----------------
// all f32->f16 weight/state conversions in one grid-strided launch
__global__ __launch_bounds__(256) void k_prep_cvt(
    const float* __restrict__ x, const float* __restrict__ h,
    const float* __restrict__ Wi, const float* __restrict__ Wh, const float* __restrict__ Wih,
    __half* __restrict__ x_h, __half* __restrict__ h_h,
    __half* __restrict__ Wi_h, __half* __restrict__ Wh_h, __half* __restrict__ Wih_h) {
  int gq = blockIdx.x * 256 + threadIdx.x;
  const float* src; __half* dst; int iq; int nin;
  if      (gq < 524288)  { src = x;   dst = x_h;   iq = gq;           nin = 2097152; }
  else if (gq < 1048576) { src = h;   dst = h_h;   iq = gq - 524288;  nin = 2097152; }
  else if (gq < 1327104) { src = Wi;  dst = Wi_h;  iq = gq - 1048576; nin = 1050112; }
  else if (gq < 1605632) { src = Wh;  dst = Wh_h;  iq = gq - 1327104; nin = 1050112; }
  else if (gq < 1671168) { src = Wih; dst = Wih_h; iq = gq - 1605632; nin = 262144;  }
  else return;
  int i = iq * 4;
  float4 v;
  if (i + 3 < nin) v = *(const float4*)(src + i);
  else v = make_float4(i + 0 < nin ? src[i + 0] : 0.f, i + 1 < nin ? src[i + 1] : 0.f,
                       i + 2 < nin ? src[i + 2] : 0.f, i + 3 < nin ? src[i + 3] : 0.f);
  *(__half2*)(dst + i)     = __floats2half2_rn(v.x, v.y);
  *(__half2*)(dst + i + 2) = __floats2half2_rn(v.z, v.w);
}

// vals: copy to new_vals, convert to f16, and 1/norm per row — one pass
__global__ __launch_bounds__(256) void k_prep_vals(
    const float* __restrict__ vals, float* __restrict__ nv,
    __half* __restrict__ vals_h, float* __restrict__ rmn) {
  const int row  = blockIdx.x * 4 + (threadIdx.x >> 6);
  const int lane = threadIdx.x & 63;
  const float* vr = vals + (size_t)row * HH + lane * 8;
  float4 a = *(const float4*)(vr);
  float4 b = *(const float4*)(vr + 4);
  float* nvp = nv + (size_t)row * HH + lane * 8;
  *(float4*)(nvp)     = a;
  *(float4*)(nvp + 4) = b;
  __half* vh = vals_h + (size_t)row * HH + lane * 8;
  *(__half2*)(vh)     = __floats2half2_rn(a.x, a.y);
  *(__half2*)(vh + 2) = __floats2half2_rn(a.z, a.w);
  *(__half2*)(vh + 4) = __floats2half2_rn(b.x, b.y);
  *(__half2*)(vh + 6) = __floats2half2_rn(b.z, b.w);
  float ss = a.x * a.x + a.y * a.y + a.z * a.z + a.w * a.w
           + b.x * b.x + b.y * b.y + b.z * b.z + b.w * b.w;
  ss = waveReduceSum(ss);
  if (lane == 0) rmn[row] = 1.f / fmaxf(sqrtf(ss), 1e-12f);
}

__global__ __launch_bounds__(256) void k_tr(const float* __restrict__ vals, __half* __restrict__ vT) {
  __shared__ float tile[32][33];
  int r0 = blockIdx.x * 32, c0 = blockIdx.y * 32;
  int tr = threadIdx.x >> 5, tc = threadIdx.x & 31;
#pragma unroll
  for (int p = 0; p < 4; ++p)
    tile[tr + p * 8][tc] = vals[(size_t)(r0 + tr + p * 8) * HH + c0 + tc];
  __syncthreads();
#pragma unroll
  for (int p = 0; p < 4; ++p)
    vT[(size_t)(c0 + tr + p * 8) * DICT + r0 + tc] = __float2half(tile[tc][tr + p * 8]);
}

// ---------------- main kernels ----------------
__global__ __launch_bounds__(256) void k_preact(
    const __half* __restrict__ x_h, const __half* __restrict__ h_h,
    const __half* __restrict__ Wi_h, const __half* __restrict__ Wh_h,
    const float* __restrict__ bi, const float* __restrict__ bh, float* __restrict__ pre) {
  __shared__ char smem[2 * (BM * BKT * 2 + 128 * BKT * 2)] __attribute__((aligned(16)));
  const int tid = threadIdx.x;
  const int m0 = blockIdx.y * 128, n0 = blockIdx.x * 128;
  f32x4 acc[4][4]; zero_acc4(acc);
  gemm_seg<128, 4>(x_h, HH, Wi_h, HH, m0, n0, HH, smem, tid, acc);
  gemm_seg<128, 4>(h_h, HH, Wh_h, HH, m0, n0, HH, smem, tid, acc);
  const int lane = tid & 63, wid = tid >> 6, wr = wid >> 1, wc = wid & 1;
#pragma unroll
  for (int fi = 0; fi < 4; ++fi)
#pragma unroll
    for (int fj = 0; fj < 4; ++fj)
#pragma unroll
      for (int q = 0; q < 4; ++q) {
        int n = n0 + wc * 64 + fj * 16 + (lane & 15);
        if (n < NHT) {
          int m = m0 + wr * 64 + fi * 16 + (lane >> 4) * 4 + q;
          pre[(size_t)m * PRE_LD + n] = acc[fi][fj][q] + bi[n] + bh[n];
        }
      }
}

__global__ __launch_bounds__(256) void k_gates(
    const float* __restrict__ pre, const float* __restrict__ c_prev,
    const float* __restrict__ x, const float* __restrict__ h,
    const float* __restrict__ Wi, const float* __restrict__ Wh,
    const float* __restrict__ bi, const float* __restrict__ bh,
    float* __restrict__ ct, float* __restrict__ ot, __half* __restrict__ ct_h,
    float* __restrict__ inps, float* __restrict__ leak,
    float* __restrict__ comp, float* __restrict__ rqn) {
  const int b = blockIdx.x, t = threadIdx.x;
  const float* row = pre + (size_t)b * PRE_LD;
  float ss = 0.f;
#pragma unroll
  for (int j = t; j < HH; j += 256) {
    float f  = sigmoidf_(row[j]);
    float o  = sigmoidf_(row[HH + j]);
    float ii = sigmoidf_(row[2 * HH + j]);
    float cn = tanhf(row[3 * HH + 3 + j]);
    float c  = c_prev[(size_t)b * HH + j] * f + ii * cn;
    size_t off = (size_t)b * HH + j;
    ct[off] = c; ot[off] = o; ct_h[off] = __float2half(c);
    ss += c * c;
  }
  ss = waveReduceSum(ss);
  __shared__ float ps[4];
  if ((t & 63) == 0) ps[t >> 6] = ss;
  // exact fp32 LCA scalar gates (cols 1536..1538)
  const int wid = t >> 6, lane = t & 63;
  float sg = 0.f;
  if (wid < 3) {
    const float* wi = Wi + (size_t)(3 * HH + wid) * HH;
    const float* wh = Wh + (size_t)(3 * HH + wid) * HH;
#pragma unroll
    for (int j = lane; j < HH; j += 64)
      sg += x[(size_t)b * HH + j] * wi[j] + h[(size_t)b * HH + j] * wh[j];
    sg = waveReduceSum(sg);
  }
  __syncthreads();
  if (t == 0) rqn[b] = 1.f / fmaxf(sqrtf(ps[0] + ps[1] + ps[2] + ps[3]), 1e-12f);
  if (wid < 3 && lane == 0) {
    float v = sigmoidf_(sg + bi[3 * HH + wid] + bh[3 * HH + wid]);
    if (wid == 0) inps[b] = v; else if (wid == 1) leak[b] = v; else comp[b] = v;
  }
}

__global__ __launch_bounds__(256) void k_sim(
    const __half* __restrict__ ct_h, const __half* __restrict__ vals_h,
    const float* __restrict__ rqn, const float* __restrict__ rmn, float* __restrict__ sim) {
  __shared__ char smem[2 * (BM * BKT * 2 + 128 * BKT * 2)] __attribute__((aligned(16)));
  const int tid = threadIdx.x;
  const int m0 = blockIdx.y * 128, n0 = blockIdx.x * 128;
  f32x4 acc[4][4]; zero_acc4(acc);
  gemm_seg<128, 4>(ct_h, HH, vals_h, HH, m0, n0, HH, smem, tid, acc);
  const int lane = tid & 63, wid = tid >> 6, wr = wid >> 1, wc = wid & 1;
#pragma unroll
  for (int fi = 0; fi < 4; ++fi)
#pragma unroll
    for (int fj = 0; fj < 4; ++fj)
#pragma unroll
      for (int q = 0; q < 4; ++q) {
        int m = m0 + wr * 64 + fi * 16 + (lane >> 4) * 4 + q;
        int n = n0 + wc * 64 + fj * 16 + (lane & 15);
        sim[(size_t)m * DICT + n] = acc[fi][fj][q] * rqn[m] * rmn[n];
      }
}

__global__ __launch_bounds__(256) void k_lca(
    const float* __restrict__ sim, const float* __restrict__ inps,
    const float* __restrict__ leak, const float* __restrict__ comp, __half* __restrict__ w_h) {
  const int b = blockIdx.x, t = threadIdx.x;
  const float* srow = sim + (size_t)b * DICT;
  const float ffs = DTT * inps[b];
  const float a   = 1.0f - DTT * leak[b] + DTT * comp[b];
  const float cdt = DTT * comp[b];
  float ff[32], V[32];
#pragma unroll
  for (int i = 0; i < 32; ++i) { ff[i] = ffs * srow[t + i * 256]; V[i] = 0.f; }
  __shared__ float ps[4];
  for (int it = 0; it < NCYC; ++it) {
    float s = 0.f;
#pragma unroll
    for (int i = 0; i < 32; ++i) s += V[i];
    s = waveReduceSum(s);
    if ((t & 63) == 0) ps[t >> 6] = s;
    __syncthreads();
    float S = ps[0] + ps[1] + ps[2] + ps[3];
    __syncthreads();
    float sub = cdt * S;
#pragma unroll
    for (int i = 0; i < 32; ++i) V[i] = fmaxf(fmaf(a, V[i], ff[i] - sub), 0.f);
  }
  __half* wrow = w_h + (size_t)b * DICT;
#pragma unroll
  for (int i = 0; i < 32; ++i) wrow[t + i * 256] = __float2half(V[i]);
}

// split-K partial GEMM: m_t partial[s] = w[:, s*2048:(s+1)*2048] @ vT[:, same]^T
// bid -> (m,n,s) XCD-bijective: each XCD owns exactly one K-stripe s, so its
// vT working set is 2 MB (L2-resident) and w is fetched exactly once.
__global__ __launch_bounds__(256) void k_mt_p(
    const __half* __restrict__ w_h, const __half* __restrict__ vT_h,
    float* __restrict__ partial) {
  __shared__ char smem[2 * (BM * BKT * 2 + 64 * BKT * 2)] __attribute__((aligned(16)));
  const int tid = threadIdx.x, bid = blockIdx.x;
  const int xcd = bid & 7, idx = bid >> 3;
  const int n = idx & 7, q = idx >> 3;
  const int g = (q << 3) | xcd;     // g = m*4 + s
  const int m = g >> 2, s = g & 3;
  const int m0 = m * 128, n0 = n * 64;
  f32x4 acc[4][2]; zero_acc2(acc);
  gemm_seg<64, 2>(w_h + s * 2048, DICT, vT_h + s * 2048, DICT, m0, n0, 2048, smem, tid, acc);
  const int lane = tid & 63, wid = tid >> 6, wr = wid >> 1, wc = wid & 1;
  float* pbase = partial + (size_t)s * (BATCH * HH);
#pragma unroll
  for (int fi = 0; fi < 4; ++fi)
#pragma unroll
    for (int fj = 0; fj < 2; ++fj)
#pragma unroll
      for (int qq = 0; qq < 4; ++qq) {
        int mm = m0 + wr * 64 + fi * 16 + (lane >> 4) * 4 + qq;
        int nn = n0 + wc * 32 + fj * 16 + (lane & 15);
        pbase[(size_t)mm * HH + nn] = acc[fi][fj][qq];
      }
}

// reduce 4 partials + full epilogue (cm, ht, nv scatter, ht_h)
__global__ __launch_bounds__(256) void k_mt_red(
    const float* __restrict__ partial,
    const float* __restrict__ ct, const float* __restrict__ ot, const int* __restrict__ mptr,
    float* __restrict__ out_mt, float* __restrict__ out_cmt, float* __restrict__ out_ht,
    float* __restrict__ out_nv, __half* __restrict__ ht_h) {
  const int i4 = blockIdx.x * 256 + threadIdx.x;
  const size_t off = (size_t)i4 * 4;
  const int m = i4 >> 7;
  float4 p  = *(const float4*)(partial + off);
  float4 p1 = *(const float4*)(partial + 2097152 + off);
  float4 p2 = *(const float4*)(partial + 4194304 + off);
  float4 p3 = *(const float4*)(partial + 6291456 + off);
  p.x += p1.x + p2.x + p3.x;
  p.y += p1.y + p2.y + p3.y;
  p.z += p1.z + p2.z + p3.z;
  p.w += p1.w + p2.w + p3.w;
  float4 c4 = *(const float4*)(ct + off);
  float4 o4 = *(const float4*)(ot + off);
  float4 cm, hv;
  cm.x = c4.x + p.x; hv.x = o4.x * tanhf(cm.x);
  cm.y = c4.y + p.y; hv.y = o4.y * tanhf(cm.y);
  cm.z = c4.z + p.z; hv.z = o4.z * tanhf(cm.z);
  cm.w = c4.w + p.w; hv.w = o4.w * tanhf(cm.w);
  *(float4*)(out_mt + off)  = p;
  *(float4*)(out_cmt + off) = cm;
  *(float4*)(out_ht + off)  = hv;
  *(__half2*)(ht_h + off)     = __floats2half2_rn(hv.x, hv.y);
  *(__half2*)(ht_h + off + 2) = __floats2half2_rn(hv.z, hv.w);
  const int nvrow = (mptr[0] + m) & (DICT - 1);
  *(float4*)(out_nv + (size_t)nvrow * HH + (off & 511)) = cm;
}

__global__ __launch_bounds__(256) void k_a2c(
    const __half* __restrict__ ht_h, const __half* __restrict__ Wih_h,
    const float* __restrict__ bih, float* __restrict__ a2c) {
  __shared__ char smem[2 * (BM * BKT * 2 + 64 * BKT * 2)] __attribute__((aligned(16)));
  const int tid = threadIdx.x;
  const int bid = blockIdx.x;
  const int xn = (bid >> 3) & 7, ym = (bid & 7) | ((bid >> 6) << 3);
  const int m0 = ym * 128, n0 = xn * 64;
  f32x4 acc[4][2]; zero_acc2(acc);
  gemm_seg<64, 2>(ht_h, HH, Wih_h, HH, m0, n0, HH, smem, tid, acc);
  const int lane = tid & 63, wid = tid >> 6, wr = wid >> 1, wc = wid & 1;
#pragma unroll
  for (int fi = 0; fi < 4; ++fi)
#pragma unroll
    for (int fj = 0; fj < 2; ++fj)
#pragma unroll
      for (int q = 0; q < 4; ++q) {
        int m = m0 + wr * 64 + fi * 16 + (lane >> 4) * 4 + q;
        int n = n0 + wc * 32 + fj * 16 + (lane & 15);
        a2c[(size_t)m * HH + n] = fmaxf(acc[fi][fj][q] + bih[n], 0.f);
      }
}

__global__ __launch_bounds__(256) void k_actor(
    const float* __restrict__ a2c,
    const float* __restrict__ Wact, const float* __restrict__ bact,
    const float* __restrict__ Wcr, const float* __restrict__ bcr,
    float* __restrict__ out_pi, float* __restrict__ out_val) {
  const int b = blockIdx.x * 4 + (threadIdx.x >> 6);
  const int lane = threadIdx.x & 63;
  const float* hrow = a2c + (size_t)b * HH;
  float4 a0 = *(const float4*)(hrow + (lane << 3));
  float4 a1 = *(const float4*)(hrow + (lane << 3) + 4);
  float lg[17];
#pragma unroll
  for (int o = 0; o < 17; ++o) {
    const float* wr = (o < 16) ? (Wact + (size_t)o * HH) : Wcr;
    float4 w0 = *(const float4*)(wr + (lane << 3));
    float4 w1 = *(const float4*)(wr + (lane << 3) + 4);
    float s = a0.x * w0.x + a0.y * w0.y + a0.z * w0.z + a0.w * w0.w
            + a1.x * w1.x + a1.y * w1.y + a1.z * w1.z + a1.w * w1.w;
    lg[o] = waveReduceSum(s);
  }
#pragma unroll
  for (int o = 0; o < 16; ++o) lg[o] += bact[o];
  float mx = lg[0];
#pragma unroll
  for (int o = 1; o < 16; ++o) mx = fmaxf(mx, lg[o]);
  float e[16], sum = 0.f;
#pragma unroll
  for (int o = 0; o < 16; ++o) { e[o] = __expf(lg[o] - mx); sum += e[o]; }
  float rs = 1.f / sum;
  if (lane == 0) {
#pragma unroll
    for (int o = 0; o < 16; ++o) out_pi[(size_t)b * 16 + o] = e[o] * rs;
    out_val[b] = lg[16] + bcr[0];
  }
}

// ---------------- launch ----------------
extern "C" void kernel_launch(void* const* d_in, const int* in_sizes, int n_in,
                              void* d_out, int out_size, void* d_ws, size_t ws_size,
                              hipStream_t stream) {
  const float* x    = (const float*)d_in[0];
  const float* h    = (const float*)d_in[1];
  const float* c    = (const float*)d_in[2];
  const float* Wi   = (const float*)d_in[3];
  const float* bi   = (const float*)d_in[4];
  const float* Wh   = (const float*)d_in[5];
  const float* bh   = (const float*)d_in[6];
  const float* vals = (const float*)d_in[7];
  const float* Wih  = (const float*)d_in[8];
  const float* bih  = (const float*)d_in[9];
  const float* Wact = (const float*)d_in[10];
  const float* bact = (const float*)d_in[11];
  const float* Wcr  = (const float*)d_in[12];
  const float* bcr  = (const float*)d_in[13];
  const int*   mptr = (const int*)d_in[14];

  float* F = (float*)d_ws;
  // region P (16,777,216 f): pre (until k_gates), then w_h (k_lca -> k_mt_p)
  float*  pre    = F;
  __half* w_h    = (__half*)F;
  // region S (33,554,432 f): sim (k_sim -> k_lca); after k_lca it is dead:
  //   a2c   = first 2M floats   (k_a2c -> k_actor)
  //   partial = 8M floats at +16M (k_mt_p -> k_mt_red)
  float*  sim     = F + 16777216;
  float*  a2c     = sim;
  float*  partial = sim + 16777216;
  float*  ct     = F + 50331648;   // 2,097,152
  float*  ot     = F + 52428800;   // 2,097,152
  __half* ct_h   = (__half*)(F + 54525952);  // 1,048,576 f
  __half* vals_h = (__half*)(F + 55574528);  // 2,097,152 f
  __half* vT_h   = (__half*)(F + 57671680);  // 2,097,152 f
  __half* x_h    = (__half*)(F + 59768832);  // 1,048,576 f (later reused as ht_h)
  __half* ht_h   = x_h;
  __half* h_h    = (__half*)(F + 60817408);  // 1,048,576 f
  __half* Wi_h   = (__half*)(F + 61865984);  // 557,056 f (2176x512)
  __half* Wh_h   = (__half*)(F + 62423040);  // 557,056 f
  __half* Wih_h  = (__half*)(F + 62980096);  // 131,072 f
  float*  inps   = F + 63111168;
  float*  leak   = inps + 4096;
  float*  comp   = leak + 4096;
  float*  rqn    = comp + 4096;
  float*  rmn    = rqn + 4096;     // 8192

  float* out     = (float*)d_out;
  float* out_pi  = out;
  float* out_val = out + 65536;
  float* out_ht  = out + 69632;
  float* out_cmt = out_ht + 2097152;
  float* out_mt  = out_cmt + 2097152;
  float* out_nv  = out_mt + 2097152;

  dim3 b256(256);
  // fused prep
  k_prep_cvt <<<6528, b256, 0, stream>>>(x, h, Wi, Wh, Wih, x_h, h_h, Wi_h, Wh_h, Wih_h);
  k_prep_vals<<<2048, b256, 0, stream>>>(vals, out_nv, vals_h, rmn);
  k_tr <<<dim3(256, 16), b256, 0, stream>>>(vals, vT_h);
  // main pipeline
  k_preact<<<dim3(17, 32), b256, 0, stream>>>(x_h, h_h, Wi_h, Wh_h, bi, bh, pre);
  k_gates <<<BATCH, b256, 0, stream>>>(pre, c, x, h, Wi, Wh, bi, bh,
                                       ct, ot, ct_h, inps, leak, comp, rqn);
  k_sim   <<<dim3(64, 32), b256, 0, stream>>>(ct_h, vals_h, rqn, rmn, sim);
  k_lca   <<<BATCH, b256, 0, stream>>>(sim, inps, leak, comp, w_h);
  k_mt_p  <<<1024, b256, 0, stream>>>(w_h, vT_h, partial);
  k_mt_red<<<2048, b256, 0, stream>>>(partial, ct, ot, mptr,
                                      out_mt, out_cmt, out_ht, out_nv, ht_h);
  k_a2c   <<<256, b256, 0, stream>>>(ht_h, Wih_h, bih, a2c);
  k_actor <<<BATCH / 4, b256, 0, stream>>>(a2c, Wact, bact, Wcr, bcr, out_pi, out_val);
}

// Round 4
// 234.750 us; speedup vs baseline: 5.8336x; 1.1029x over previous
//
#include <hip/hip_runtime.h>
#include <hip/hip_fp16.h>
#include <math.h>

#define HH    512
#define DICT  8192
#define BATCH 4096
#define NCYC  10
#define DTT   0.6f

#define BM  128
#define BKT 64    // K elements per tile; row = 128 bytes = 8 chunks of 16B

using f16x8 = __attribute__((ext_vector_type(8))) _Float16;
using f32x4 = __attribute__((ext_vector_type(4))) float;

__device__ __forceinline__ float sigmoidf_(float x) { return 1.0f / (1.0f + __expf(-x)); }

__device__ __forceinline__ float waveReduceSum(float v) {
#pragma unroll
  for (int o = 1; o < 64; o <<= 1) v += __shfl_xor(v, o);
  return v;
}

__device__ __forceinline__ void gld16(const void* g, void* l) {
  __builtin_amdgcn_global_load_lds(
      (const __attribute__((address_space(1))) void*)g,
      (__attribute__((address_space(3))) void*)l, 16, 0, 0);
}

// Stage ROWS x 64 f16 tile. LDS linear (global_load_lds rule), source pre-swizzled:
// data chunk k4 of row r lands in LDS slot (k4 ^ (r&7)).
template<int ROWS>
__device__ __forceinline__ void stage_tile(const __half* gbase, int ld, char* lds, int tid) {
  constexpr int ISS = ROWS * 8 / 256;
#pragma unroll
  for (int i = 0; i < ISS; ++i) {
    int cidx = i * 256 + tid;
    int row  = cidx >> 3;
    int slot = cidx & 7;
    int k4   = slot ^ (row & 7);
    gld16(gbase + (size_t)row * ld + k4 * 8, lds + cidx * 16);
  }
}

__device__ __forceinline__ f16x8 frag_ld(const char* lds, int row, int kchunk) {
  int slot = kchunk ^ (row & 7);
  return *(const f16x8*)(lds + row * 128 + slot * 16);
}

template<int FN>
__device__ __forceinline__ void tile_mfma(const char* As, const char* Bs,
                                          int lane, int wr, int wc, f32x4 (&acc)[4][FN]) {
  const int g = lane >> 4, r = lane & 15;
#pragma unroll
  for (int ks = 0; ks < 2; ++ks) {
    f16x8 af[4], bfr[FN];
#pragma unroll
    for (int i = 0; i < 4; ++i)
      af[i] = frag_ld(As, wr * 64 + i * 16 + r, ks * 4 + g);
#pragma unroll
    for (int j = 0; j < FN; ++j)
      bfr[j] = frag_ld(Bs, wc * (FN * 16) + j * 16 + r, ks * 4 + g);
#pragma unroll
    for (int i = 0; i < 4; ++i)
#pragma unroll
      for (int j = 0; j < FN; ++j)
        acc[i][j] = __builtin_amdgcn_mfma_f32_16x16x32_f16(af[i], bfr[j], acc[i][j], 0, 0, 0);
  }
}

// C[m,n] += sum_k A[m,k]*B[n,k], both f16 k-contiguous (NT). 2-phase dbuf prefetch.
template<int BN, int FN>
__device__ __forceinline__ void gemm_seg(const __half* A, int lda, const __half* B, int ldb,
                                         int m0, int n0, int K, char* lds, int tid,
                                         f32x4 (&acc)[4][FN]) {
  constexpr int ABYTES = BM * BKT * 2;
  constexpr int BBYTES = BN * BKT * 2;
  const int lane = tid & 63, wid = tid >> 6;
  const int wr = wid >> 1, wc = wid & 1;
  const int nt = K / BKT;
  const __half* Ab = A + (size_t)m0 * lda;
  const __half* Bb = B + (size_t)n0 * ldb;
  stage_tile<BM>(Ab, lda, lds, tid);
  stage_tile<BN>(Bb, ldb, lds + ABYTES, tid);
  __syncthreads();
  int cur = 0;
  for (int t = 0; t < nt - 1; ++t) {
    char* nxt = lds + (cur ^ 1) * (ABYTES + BBYTES);
    stage_tile<BM>(Ab + (t + 1) * BKT, lda, nxt, tid);
    stage_tile<BN>(Bb + (t + 1) * BKT, ldb, nxt + ABYTES, tid);
    char* curb = lds + cur * (ABYTES + BBYTES);
    tile_mfma<FN>(curb, curb + ABYTES, lane, wr, wc, acc);
    __syncthreads();
    cur ^= 1;
  }
  char* curb = lds + cur * (ABYTES + BBYTES);
  tile_mfma<FN>(curb, curb + ABYTES, lane, wr, wc, acc);
  __syncthreads();
}

__device__ __forceinline__ void zero_acc4(f32x4 (&a)[4][4]) {
  f32x4 z = {0.f, 0.f, 0.f, 0.f};
#pragma unroll
  for (int i = 0; i < 4; ++i)
#pragma unroll
    for (int j = 0; j < 4; ++j) a[i][j] = z;
}
__device__ __forceinline__ void zero_acc2(f32x4 (&a)[4][2]) {
  f32x4 z = {0.f, 0.f, 0.f, 0.f};
#pragma unroll
  for (int i = 0; i < 4; ++i)
#pragma unroll
    for (int j = 0; j < 2; ++j) a[i][j] = z;
}

// ---------------- fused prep kernels ----------------
// f32->f16 converts; Wi/Wh are written PERMUTED to gate-interleaved layout:
// out row j' = 64*U + 16*g + r  -> orig row  g*512 + (16*U + r) + (g==3 ? 3 : 0)
// (g: 0=f,1=o,2=i,3=c_new; u = 16U+r in [0,512))
__global__ __launch_bounds__(256) void k_prep_cvt(
    const float* __restrict__ x, const float* __restrict__ h,
    const float* __restrict__ Wi, const float* __restrict__ Wh, const float* __restrict__ Wih,
    __half* __restrict__ x_h, __half* __restrict__ h_h,
    __half* __restrict__ Wip_h, __half* __restrict__ Whp_h, __half* __restrict__ Wih_h) {
  int gq = blockIdx.x * 256 + threadIdx.x;
  const float* src; __half* dst; int si, di;
  if (gq < 524288) {                    // x
    src = x; dst = x_h; si = di = gq * 4;
  } else if (gq < 1048576) {            // h
    src = h; dst = h_h; si = di = (gq - 524288) * 4;
  } else if (gq < 1310720) {            // Wi permuted
    int iq = gq - 1048576;
    int jp = iq >> 7, k4 = (iq & 127) << 2;
    int U = jp >> 6, g = (jp >> 4) & 3, r = jp & 15;
    int u = U * 16 + r;
    int orig = g * 512 + u + (g == 3 ? 3 : 0);
    src = Wi; dst = Wip_h; si = orig * 512 + k4; di = jp * 512 + k4;
  } else if (gq < 1572864) {            // Wh permuted
    int iq = gq - 1310720;
    int jp = iq >> 7, k4 = (iq & 127) << 2;
    int U = jp >> 6, g = (jp >> 4) & 3, r = jp & 15;
    int u = U * 16 + r;
    int orig = g * 512 + u + (g == 3 ? 3 : 0);
    src = Wh; dst = Whp_h; si = orig * 512 + k4; di = jp * 512 + k4;
  } else if (gq < 1638400) {            // Wih
    int iq = gq - 1572864;
    src = Wih; dst = Wih_h; si = di = iq * 4;
  } else return;
  float4 v = *(const float4*)(src + si);
  *(__half2*)(dst + di)     = __floats2half2_rn(v.x, v.y);
  *(__half2*)(dst + di + 2) = __floats2half2_rn(v.z, v.w);
}

// vals: copy to new_vals, convert to f16, and 1/norm per row — one pass
__global__ __launch_bounds__(256) void k_prep_vals(
    const float* __restrict__ vals, float* __restrict__ nv,
    __half* __restrict__ vals_h, float* __restrict__ rmn) {
  const int row  = blockIdx.x * 4 + (threadIdx.x >> 6);
  const int lane = threadIdx.x & 63;
  const float* vr = vals + (size_t)row * HH + lane * 8;
  float4 a = *(const float4*)(vr);
  float4 b = *(const float4*)(vr + 4);
  float* nvp = nv + (size_t)row * HH + lane * 8;
  *(float4*)(nvp)     = a;
  *(float4*)(nvp + 4) = b;
  __half* vh = vals_h + (size_t)row * HH + lane * 8;
  *(__half2*)(vh)     = __floats2half2_rn(a.x, a.y);
  *(__half2*)(vh + 2) = __floats2half2_rn(a.z, a.w);
  *(__half2*)(vh + 4) = __floats2half2_rn(b.x, b.y);
  *(__half2*)(vh + 6) = __floats2half2_rn(b.z, b.w);
  float ss = a.x * a.x + a.y * a.y + a.z * a.z + a.w * a.w
           + b.x * b.x + b.y * b.y + b.z * b.z + b.w * b.w;
  ss = waveReduceSum(ss);
  if (lane == 0) rmn[row] = 1.f / fmaxf(sqrtf(ss), 1e-12f);
}

__global__ __launch_bounds__(256) void k_tr(const float* __restrict__ vals, __half* __restrict__ vT) {
  __shared__ float tile[32][33];
  int r0 = blockIdx.x * 32, c0 = blockIdx.y * 32;
  int tr = threadIdx.x >> 5, tc = threadIdx.x & 31;
#pragma unroll
  for (int p = 0; p < 4; ++p)
    tile[tr + p * 8][tc] = vals[(size_t)(r0 + tr + p * 8) * HH + c0 + tc];
  __syncthreads();
#pragma unroll
  for (int p = 0; p < 4; ++p)
    vT[(size_t)(c0 + tr + p * 8) * DICT + r0 + tc] = __float2half(tile[tc][tr + p * 8]);
}

// ---------------- main kernels ----------------
// fused preact GEMM + LSTM gates: weights are gate-interleaved so fragment
// fj == gate g for hidden unit u = 16*((n0>>6)+wc) + (lane&15).
__global__ __launch_bounds__(256) void k_preact(
    const __half* __restrict__ x_h, const __half* __restrict__ h_h,
    const __half* __restrict__ Wip, const __half* __restrict__ Whp,
    const float* __restrict__ bi, const float* __restrict__ bh,
    const float* __restrict__ c_prev,
    float* __restrict__ ct, float* __restrict__ ot, __half* __restrict__ ct_h) {
  __shared__ char smem[2 * (BM * BKT * 2 + 128 * BKT * 2)] __attribute__((aligned(16)));
  const int tid = threadIdx.x;
  const int m0 = blockIdx.y * 128, n0 = blockIdx.x * 128;
  f32x4 acc[4][4]; zero_acc4(acc);
  gemm_seg<128, 4>(x_h, HH, Wip, HH, m0, n0, HH, smem, tid, acc);
  gemm_seg<128, 4>(h_h, HH, Whp, HH, m0, n0, HH, smem, tid, acc);
  const int lane = tid & 63, wid = tid >> 6, wr = wid >> 1, wc = wid & 1;
  const int r = lane & 15;
  const int u = ((n0 >> 6) + wc) * 16 + r;
  float bsum[4];
#pragma unroll
  for (int g = 0; g < 4; ++g) {
    int orig = g * 512 + u + (g == 3 ? 3 : 0);
    bsum[g] = bi[orig] + bh[orig];
  }
#pragma unroll
  for (int fi = 0; fi < 4; ++fi)
#pragma unroll
    for (int q = 0; q < 4; ++q) {
      int m = m0 + wr * 64 + fi * 16 + (lane >> 4) * 4 + q;
      float f  = sigmoidf_(acc[fi][0][q] + bsum[0]);
      float o  = sigmoidf_(acc[fi][1][q] + bsum[1]);
      float ii = sigmoidf_(acc[fi][2][q] + bsum[2]);
      float cn = tanhf(acc[fi][3][q] + bsum[3]);
      size_t off = (size_t)m * HH + u;
      float cc = c_prev[off] * f + ii * cn;
      ct[off] = cc; ot[off] = o; ct_h[off] = __float2half(cc);
    }
}

// exact fp32 LCA scalar gates (orig cols 1536..1538) + rqn from ct
__global__ __launch_bounds__(256) void k_scalars(
    const float* __restrict__ x, const float* __restrict__ h,
    const float* __restrict__ Wi, const float* __restrict__ Wh,
    const float* __restrict__ bi, const float* __restrict__ bh,
    const float* __restrict__ ct,
    float* __restrict__ inps, float* __restrict__ leak,
    float* __restrict__ comp, float* __restrict__ rqn) {
  const int b = blockIdx.x, wid = threadIdx.x >> 6, lane = threadIdx.x & 63;
  const int j = lane * 8;
  if (wid < 3) {
    const float* wi = Wi + (size_t)(1536 + wid) * HH + j;
    const float* wh = Wh + (size_t)(1536 + wid) * HH + j;
    const float* xr = x + (size_t)b * HH + j;
    const float* hr = h + (size_t)b * HH + j;
    float4 xa = *(const float4*)(xr), xb = *(const float4*)(xr + 4);
    float4 wa = *(const float4*)(wi), wb = *(const float4*)(wi + 4);
    float4 ha = *(const float4*)(hr), hb = *(const float4*)(hr + 4);
    float4 va = *(const float4*)(wh), vb = *(const float4*)(wh + 4);
    float s = xa.x * wa.x + xa.y * wa.y + xa.z * wa.z + xa.w * wa.w
            + xb.x * wb.x + xb.y * wb.y + xb.z * wb.z + xb.w * wb.w
            + ha.x * va.x + ha.y * va.y + ha.z * va.z + ha.w * va.w
            + hb.x * vb.x + hb.y * vb.y + hb.z * vb.z + hb.w * vb.w;
    s = waveReduceSum(s);
    if (lane == 0) {
      float v = sigmoidf_(s + bi[1536 + wid] + bh[1536 + wid]);
      if (wid == 0) inps[b] = v; else if (wid == 1) leak[b] = v; else comp[b] = v;
    }
  } else {
    const float* cr = ct + (size_t)b * HH + j;
    float4 a = *(const float4*)(cr), d = *(const float4*)(cr + 4);
    float ss = a.x * a.x + a.y * a.y + a.z * a.z + a.w * a.w
             + d.x * d.x + d.y * d.y + d.z * d.z + d.w * d.w;
    ss = waveReduceSum(ss);
    if (lane == 0) rqn[b] = 1.f / fmaxf(sqrtf(ss), 1e-12f);
  }
}

__global__ __launch_bounds__(256) void k_sim(
    const __half* __restrict__ ct_h, const __half* __restrict__ vals_h,
    const float* __restrict__ rqn, const float* __restrict__ rmn,
    __half* __restrict__ sim_h) {
  __shared__ char smem[2 * (BM * BKT * 2 + 128 * BKT * 2)] __attribute__((aligned(16)));
  const int tid = threadIdx.x;
  const int m0 = blockIdx.y * 128, n0 = blockIdx.x * 128;
  f32x4 acc[4][4]; zero_acc4(acc);
  gemm_seg<128, 4>(ct_h, HH, vals_h, HH, m0, n0, HH, smem, tid, acc);
  const int lane = tid & 63, wid = tid >> 6, wr = wid >> 1, wc = wid & 1;
#pragma unroll
  for (int fi = 0; fi < 4; ++fi)
#pragma unroll
    for (int fj = 0; fj < 4; ++fj)
#pragma unroll
      for (int q = 0; q < 4; ++q) {
        int m = m0 + wr * 64 + fi * 16 + (lane >> 4) * 4 + q;
        int n = n0 + wc * 64 + fj * 16 + (lane & 15);
        sim_h[(size_t)m * DICT + n] = __float2half(acc[fi][fj][q] * rqn[m] * rmn[n]);
      }
}

// LCA: thread owns 32 CONTIGUOUS dict elems (64B vector loads/stores, f16)
__global__ __launch_bounds__(256) void k_lca(
    const __half* __restrict__ sim_h, const float* __restrict__ inps,
    const float* __restrict__ leak, const float* __restrict__ comp,
    __half* __restrict__ w_h) {
  const int b = blockIdx.x, t = threadIdx.x;
  const __half* srow = sim_h + (size_t)b * DICT + t * 32;
  const float ffs = DTT * inps[b];
  const float a   = 1.0f - DTT * leak[b] + DTT * comp[b];
  const float cdt = DTT * comp[b];
  float ff[32], V[32];
#pragma unroll
  for (int i = 0; i < 4; ++i) {
    f16x8 v8 = *(const f16x8*)(srow + i * 8);
#pragma unroll
    for (int j = 0; j < 8; ++j) { ff[i * 8 + j] = ffs * (float)v8[j]; V[i * 8 + j] = 0.f; }
  }
  __shared__ float ps[4];
  for (int it = 0; it < NCYC; ++it) {
    float s = 0.f;
#pragma unroll
    for (int i = 0; i < 32; ++i) s += V[i];
    s = waveReduceSum(s);
    if ((t & 63) == 0) ps[t >> 6] = s;
    __syncthreads();
    float S = ps[0] + ps[1] + ps[2] + ps[3];
    __syncthreads();
    float sub = cdt * S;
#pragma unroll
    for (int i = 0; i < 32; ++i) V[i] = fmaxf(fmaf(a, V[i], ff[i] - sub), 0.f);
  }
  __half* wrow = w_h + (size_t)b * DICT + t * 32;
#pragma unroll
  for (int i = 0; i < 4; ++i) {
    f16x8 o8;
#pragma unroll
    for (int j = 0; j < 8; ++j) o8[j] = (_Float16)V[i * 8 + j];
    *(f16x8*)(wrow + i * 8) = o8;
  }
}

// split-K partial GEMM; bid -> (m,n,s) XCD-bijective: each XCD owns one K-stripe
__global__ __launch_bounds__(256) void k_mt_p(
    const __half* __restrict__ w_h, const __half* __restrict__ vT_h,
    float* __restrict__ partial) {
  __shared__ char smem[2 * (BM * BKT * 2 + 64 * BKT * 2)] __attribute__((aligned(16)));
  const int tid = threadIdx.x, bid = blockIdx.x;
  const int xcd = bid & 7, idx = bid >> 3;
  const int n = idx & 7, q = idx >> 3;
  const int g = (q << 3) | xcd;     // g = m*4 + s
  const int m = g >> 2, s = g & 3;
  const int m0 = m * 128, n0 = n * 64;
  f32x4 acc[4][2]; zero_acc2(acc);
  gemm_seg<64, 2>(w_h + s * 2048, DICT, vT_h + s * 2048, DICT, m0, n0, 2048, smem, tid, acc);
  const int lane = tid & 63, wid = tid >> 6, wr = wid >> 1, wc = wid & 1;
  float* pbase = partial + (size_t)s * (BATCH * HH);
#pragma unroll
  for (int fi = 0; fi < 4; ++fi)
#pragma unroll
    for (int fj = 0; fj < 2; ++fj)
#pragma unroll
      for (int qq = 0; qq < 4; ++qq) {
        int mm = m0 + wr * 64 + fi * 16 + (lane >> 4) * 4 + qq;
        int nn = n0 + wc * 32 + fj * 16 + (lane & 15);
        pbase[(size_t)mm * HH + nn] = acc[fi][fj][qq];
      }
}

// reduce 4 partials + full epilogue (cm, ht, nv scatter, ht_h)
__global__ __launch_bounds__(256) void k_mt_red(
    const float* __restrict__ partial,
    const float* __restrict__ ct, const float* __restrict__ ot, const int* __restrict__ mptr,
    float* __restrict__ out_mt, float* __restrict__ out_cmt, float* __restrict__ out_ht,
    float* __restrict__ out_nv, __half* __restrict__ ht_h) {
  const int i4 = blockIdx.x * 256 + threadIdx.x;
  const size_t off = (size_t)i4 * 4;
  const int m = i4 >> 7;
  float4 p  = *(const float4*)(partial + off);
  float4 p1 = *(const float4*)(partial + 2097152 + off);
  float4 p2 = *(const float4*)(partial + 4194304 + off);
  float4 p3 = *(const float4*)(partial + 6291456 + off);
  p.x += p1.x + p2.x + p3.x;
  p.y += p1.y + p2.y + p3.y;
  p.z += p1.z + p2.z + p3.z;
  p.w += p1.w + p2.w + p3.w;
  float4 c4 = *(const float4*)(ct + off);
  float4 o4 = *(const float4*)(ot + off);
  float4 cm, hv;
  cm.x = c4.x + p.x; hv.x = o4.x * tanhf(cm.x);
  cm.y = c4.y + p.y; hv.y = o4.y * tanhf(cm.y);
  cm.z = c4.z + p.z; hv.z = o4.z * tanhf(cm.z);
  cm.w = c4.w + p.w; hv.w = o4.w * tanhf(cm.w);
  *(float4*)(out_mt + off)  = p;
  *(float4*)(out_cmt + off) = cm;
  *(float4*)(out_ht + off)  = hv;
  *(__half2*)(ht_h + off)     = __floats2half2_rn(hv.x, hv.y);
  *(__half2*)(ht_h + off + 2) = __floats2half2_rn(hv.z, hv.w);
  const int nvrow = (mptr[0] + m) & (DICT - 1);
  *(float4*)(out_nv + (size_t)nvrow * HH + (off & 511)) = cm;
}

__global__ __launch_bounds__(256) void k_a2c(
    const __half* __restrict__ ht_h, const __half* __restrict__ Wih_h,
    const float* __restrict__ bih, float* __restrict__ a2c) {
  __shared__ char smem[2 * (BM * BKT * 2 + 64 * BKT * 2)] __attribute__((aligned(16)));
  const int tid = threadIdx.x;
  const int bid = blockIdx.x;
  const int xn = (bid >> 3) & 7, ym = (bid & 7) | ((bid >> 6) << 3);
  const int m0 = ym * 128, n0 = xn * 64;
  f32x4 acc[4][2]; zero_acc2(acc);
  gemm_seg<64, 2>(ht_h, HH, Wih_h, HH, m0, n0, HH, smem, tid, acc);
  const int lane = tid & 63, wid = tid >> 6, wr = wid >> 1, wc = wid & 1;
#pragma unroll
  for (int fi = 0; fi < 4; ++fi)
#pragma unroll
    for (int fj = 0; fj < 2; ++fj)
#pragma unroll
      for (int q = 0; q < 4; ++q) {
        int m = m0 + wr * 64 + fi * 16 + (lane >> 4) * 4 + q;
        int n = n0 + wc * 32 + fj * 16 + (lane & 15);
        a2c[(size_t)m * HH + n] = fmaxf(acc[fi][fj][q] + bih[n], 0.f);
      }
}

__global__ __launch_bounds__(256) void k_actor(
    const float* __restrict__ a2c,
    const float* __restrict__ Wact, const float* __restrict__ bact,
    const float* __restrict__ Wcr, const float* __restrict__ bcr,
    float* __restrict__ out_pi, float* __restrict__ out_val) {
  const int b = blockIdx.x * 4 + (threadIdx.x >> 6);
  const int lane = threadIdx.x & 63;
  const float* hrow = a2c + (size_t)b * HH;
  float4 a0 = *(const float4*)(hrow + (lane << 3));
  float4 a1 = *(const float4*)(hrow + (lane << 3) + 4);
  float lg[17];
#pragma unroll
  for (int o = 0; o < 17; ++o) {
    const float* wr = (o < 16) ? (Wact + (size_t)o * HH) : Wcr;
    float4 w0 = *(const float4*)(wr + (lane << 3));
    float4 w1 = *(const float4*)(wr + (lane << 3) + 4);
    float s = a0.x * w0.x + a0.y * w0.y + a0.z * w0.z + a0.w * w0.w
            + a1.x * w1.x + a1.y * w1.y + a1.z * w1.z + a1.w * w1.w;
    lg[o] = waveReduceSum(s);
  }
#pragma unroll
  for (int o = 0; o < 16; ++o) lg[o] += bact[o];
  float mx = lg[0];
#pragma unroll
  for (int o = 1; o < 16; ++o) mx = fmaxf(mx, lg[o]);
  float e[16], sum = 0.f;
#pragma unroll
  for (int o = 0; o < 16; ++o) { e[o] = __expf(lg[o] - mx); sum += e[o]; }
  float rs = 1.f / sum;
  if (lane == 0) {
#pragma unroll
    for (int o = 0; o < 16; ++o) out_pi[(size_t)b * 16 + o] = e[o] * rs;
    out_val[b] = lg[16] + bcr[0];
  }
}

// ---------------- launch ----------------
extern "C" void kernel_launch(void* const* d_in, const int* in_sizes, int n_in,
                              void* d_out, int out_size, void* d_ws, size_t ws_size,
                              hipStream_t stream) {
  const float* x    = (const float*)d_in[0];
  const float* h    = (const float*)d_in[1];
  const float* c    = (const float*)d_in[2];
  const float* Wi   = (const float*)d_in[3];
  const float* bi   = (const float*)d_in[4];
  const float* Wh   = (const float*)d_in[5];
  const float* bh   = (const float*)d_in[6];
  const float* vals = (const float*)d_in[7];
  const float* Wih  = (const float*)d_in[8];
  const float* bih  = (const float*)d_in[9];
  const float* Wact = (const float*)d_in[10];
  const float* bact = (const float*)d_in[11];
  const float* Wcr  = (const float*)d_in[12];
  const float* bcr  = (const float*)d_in[13];
  const int*   mptr = (const int*)d_in[14];

  float* F = (float*)d_ws;
  // region P: w_h f16 (k_lca -> k_mt_p)
  __half* w_h    = (__half*)F;
  // region S: sim_h f16 (k_sim -> k_lca); after dead: a2c at start, partial at +16M f
  __half* sim_h   = (__half*)(F + 16777216);
  float*  a2c     = F + 16777216;
  float*  partial = F + 33554432;           // 8.4M floats
  float*  ct     = F + 50331648;            // 2,097,152
  float*  ot     = F + 52428800;            // 2,097,152
  __half* ct_h   = (__half*)(F + 54525952); // 1,048,576 f
  __half* vals_h = (__half*)(F + 55574528); // 2,097,152 f
  __half* vT_h   = (__half*)(F + 57671680); // 2,097,152 f
  __half* x_h    = (__half*)(F + 59768832); // 1,048,576 f (later reused as ht_h)
  __half* ht_h   = x_h;
  __half* h_h    = (__half*)(F + 60817408); // 1,048,576 f
  __half* Wip_h  = (__half*)(F + 61865984); // 524,288 f (2048x512 f16)
  __half* Whp_h  = (__half*)(F + 62423040); // 524,288 f
  __half* Wih_h  = (__half*)(F + 62980096); // 131,072 f
  float*  inps   = F + 63111168;
  float*  leak   = inps + 4096;
  float*  comp   = leak + 4096;
  float*  rqn    = comp + 4096;
  float*  rmn    = rqn + 4096;              // 8192

  float* out     = (float*)d_out;
  float* out_pi  = out;
  float* out_val = out + 65536;
  float* out_ht  = out + 69632;
  float* out_cmt = out_ht + 2097152;
  float* out_mt  = out_cmt + 2097152;
  float* out_nv  = out_mt + 2097152;

  dim3 b256(256);
  k_prep_cvt <<<6400, b256, 0, stream>>>(x, h, Wi, Wh, Wih, x_h, h_h, Wip_h, Whp_h, Wih_h);
  k_prep_vals<<<2048, b256, 0, stream>>>(vals, out_nv, vals_h, rmn);
  k_tr <<<dim3(256, 16), b256, 0, stream>>>(vals, vT_h);
  k_preact <<<dim3(16, 32), b256, 0, stream>>>(x_h, h_h, Wip_h, Whp_h, bi, bh, c,
                                               ct, ot, ct_h);
  k_scalars<<<BATCH, b256, 0, stream>>>(x, h, Wi, Wh, bi, bh, ct, inps, leak, comp, rqn);
  k_sim    <<<dim3(64, 32), b256, 0, stream>>>(ct_h, vals_h, rqn, rmn, sim_h);
  k_lca    <<<BATCH, b256, 0, stream>>>(sim_h, inps, leak, comp, w_h);
  k_mt_p   <<<1024, b256, 0, stream>>>(w_h, vT_h, partial);
  k_mt_red <<<2048, b256, 0, stream>>>(partial, ct, ot, mptr,
                                       out_mt, out_cmt, out_ht, out_nv, ht_h);
  k_a2c    <<<256, b256, 0, stream>>>(ht_h, Wih_h, bih, a2c);
  k_actor  <<<BATCH / 4, b256, 0, stream>>>(a2c, Wact, bact, Wcr, bcr, out_pi, out_val);
}

// Round 5
// 221.599 us; speedup vs baseline: 6.1798x; 1.0593x over previous
//
#include <hip/hip_runtime.h>
#include <hip/hip_fp16.h>
#include <math.h>

#define HH    512
#define DICT  8192
#define BATCH 4096
#define NCYC  10
#define DTT   0.6f

#define BM  128
#define BKT 64    // K elements per tile; row = 128 bytes = 8 chunks of 16B

using f16x8 = __attribute__((ext_vector_type(8))) _Float16;
using f32x4 = __attribute__((ext_vector_type(4))) float;

__device__ __forceinline__ float sigmoidf_(float x) { return 1.0f / (1.0f + __expf(-x)); }

__device__ __forceinline__ float waveReduceSum(float v) {
#pragma unroll
  for (int o = 1; o < 64; o <<= 1) v += __shfl_xor(v, o);
  return v;
}

__device__ __forceinline__ void gld16(const void* g, void* l) {
  __builtin_amdgcn_global_load_lds(
      (const __attribute__((address_space(1))) void*)g,
      (__attribute__((address_space(3))) void*)l, 16, 0, 0);
}

// Stage ROWS x 64 f16 tile. LDS linear (global_load_lds rule), source pre-swizzled:
// data chunk k4 of row r lands in LDS slot (k4 ^ (r&7)).
template<int ROWS>
__device__ __forceinline__ void stage_tile(const __half* gbase, int ld, char* lds, int tid) {
  constexpr int ISS = ROWS * 8 / 256;
#pragma unroll
  for (int i = 0; i < ISS; ++i) {
    int cidx = i * 256 + tid;
    int row  = cidx >> 3;
    int slot = cidx & 7;
    int k4   = slot ^ (row & 7);
    gld16(gbase + (size_t)row * ld + k4 * 8, lds + cidx * 16);
  }
}

__device__ __forceinline__ f16x8 frag_ld(const char* lds, int row, int kchunk) {
  int slot = kchunk ^ (row & 7);
  return *(const f16x8*)(lds + row * 128 + slot * 16);
}

template<int FN>
__device__ __forceinline__ void tile_mfma(const char* As, const char* Bs,
                                          int lane, int wr, int wc, f32x4 (&acc)[4][FN]) {
  const int g = lane >> 4, r = lane & 15;
#pragma unroll
  for (int ks = 0; ks < 2; ++ks) {
    f16x8 af[4], bfr[FN];
#pragma unroll
    for (int i = 0; i < 4; ++i)
      af[i] = frag_ld(As, wr * 64 + i * 16 + r, ks * 4 + g);
#pragma unroll
    for (int j = 0; j < FN; ++j)
      bfr[j] = frag_ld(Bs, wc * (FN * 16) + j * 16 + r, ks * 4 + g);
#pragma unroll
    for (int i = 0; i < 4; ++i)
#pragma unroll
      for (int j = 0; j < FN; ++j)
        acc[i][j] = __builtin_amdgcn_mfma_f32_16x16x32_f16(af[i], bfr[j], acc[i][j], 0, 0, 0);
  }
}

// C[m,n] += sum_k A[m,k]*B[n,k], both f16 k-contiguous (NT).
// SINGLE-buffered m97 pattern: stage -> sync(drain) -> mfma -> sync.
// Halved LDS (vs dbuf) buys +1 resident block/CU; dbuf was neutral (m99/m100)
// because __syncthreads' vmcnt(0) drain waits for the prefetch anyway.
template<int BN, int FN>
__device__ __forceinline__ void gemm_seg(const __half* A, int lda, const __half* B, int ldb,
                                         int m0, int n0, int K, char* lds, int tid,
                                         f32x4 (&acc)[4][FN]) {
  constexpr int ABYTES = BM * BKT * 2;
  const int lane = tid & 63, wid = tid >> 6;
  const int wr = wid >> 1, wc = wid & 1;
  const int nt = K / BKT;
  const __half* Ab = A + (size_t)m0 * lda;
  const __half* Bb = B + (size_t)n0 * ldb;
  for (int t = 0; t < nt; ++t) {
    stage_tile<BM>(Ab + t * BKT, lda, lds, tid);
    stage_tile<BN>(Bb + t * BKT, ldb, lds + ABYTES, tid);
    __syncthreads();
    tile_mfma<FN>(lds, lds + ABYTES, lane, wr, wc, acc);
    __syncthreads();
  }
}

__device__ __forceinline__ void zero_acc4(f32x4 (&a)[4][4]) {
  f32x4 z = {0.f, 0.f, 0.f, 0.f};
#pragma unroll
  for (int i = 0; i < 4; ++i)
#pragma unroll
    for (int j = 0; j < 4; ++j) a[i][j] = z;
}
__device__ __forceinline__ void zero_acc2(f32x4 (&a)[4][2]) {
  f32x4 z = {0.f, 0.f, 0.f, 0.f};
#pragma unroll
  for (int i = 0; i < 4; ++i)
#pragma unroll
    for (int j = 0; j < 2; ++j) a[i][j] = z;
}

// ---------------- fused prep (cvt + vals + transpose in one launch) ----------------
// blocks [0,6400): f32->f16 converts; Wi/Wh written PERMUTED gate-interleaved:
//   out row j' = 64*U + 16*g + r  -> orig row  g*512 + (16*U + r) + (g==3 ? 3 : 0)
// blocks [6400,8448): vals copy + f16 + 1/norm
// blocks [8448,12544): vals transpose -> vT f16
__global__ __launch_bounds__(256) void k_prep(
    const float* __restrict__ x, const float* __restrict__ h,
    const float* __restrict__ Wi, const float* __restrict__ Wh, const float* __restrict__ Wih,
    const float* __restrict__ vals,
    __half* __restrict__ x_h, __half* __restrict__ h_h,
    __half* __restrict__ Wip_h, __half* __restrict__ Whp_h, __half* __restrict__ Wih_h,
    float* __restrict__ nv, __half* __restrict__ vals_h, float* __restrict__ rmn,
    __half* __restrict__ vT) {
  __shared__ float tile[32][33];
  const int bid = blockIdx.x;
  if (bid < 6400) {
    int gq = bid * 256 + threadIdx.x;
    const float* src; __half* dst; int si, di;
    if (gq < 524288) {                    // x
      src = x; dst = x_h; si = di = gq * 4;
    } else if (gq < 1048576) {            // h
      src = h; dst = h_h; si = di = (gq - 524288) * 4;
    } else if (gq < 1310720) {            // Wi permuted
      int iq = gq - 1048576;
      int jp = iq >> 7, k4 = (iq & 127) << 2;
      int U = jp >> 6, g = (jp >> 4) & 3, r = jp & 15;
      int u = U * 16 + r;
      int orig = g * 512 + u + (g == 3 ? 3 : 0);
      src = Wi; dst = Wip_h; si = orig * 512 + k4; di = jp * 512 + k4;
    } else if (gq < 1572864) {            // Wh permuted
      int iq = gq - 1310720;
      int jp = iq >> 7, k4 = (iq & 127) << 2;
      int U = jp >> 6, g = (jp >> 4) & 3, r = jp & 15;
      int u = U * 16 + r;
      int orig = g * 512 + u + (g == 3 ? 3 : 0);
      src = Wh; dst = Whp_h; si = orig * 512 + k4; di = jp * 512 + k4;
    } else if (gq < 1638400) {            // Wih
      int iq = gq - 1572864;
      src = Wih; dst = Wih_h; si = di = iq * 4;
    } else return;
    float4 v = *(const float4*)(src + si);
    *(__half2*)(dst + di)     = __floats2half2_rn(v.x, v.y);
    *(__half2*)(dst + di + 2) = __floats2half2_rn(v.z, v.w);
  } else if (bid < 8448) {
    const int row  = (bid - 6400) * 4 + (threadIdx.x >> 6);
    const int lane = threadIdx.x & 63;
    const float* vr = vals + (size_t)row * HH + lane * 8;
    float4 a = *(const float4*)(vr);
    float4 b = *(const float4*)(vr + 4);
    float* nvp = nv + (size_t)row * HH + lane * 8;
    *(float4*)(nvp)     = a;
    *(float4*)(nvp + 4) = b;
    __half* vh = vals_h + (size_t)row * HH + lane * 8;
    *(__half2*)(vh)     = __floats2half2_rn(a.x, a.y);
    *(__half2*)(vh + 2) = __floats2half2_rn(a.z, a.w);
    *(__half2*)(vh + 4) = __floats2half2_rn(b.x, b.y);
    *(__half2*)(vh + 6) = __floats2half2_rn(b.z, b.w);
    float ss = a.x * a.x + a.y * a.y + a.z * a.z + a.w * a.w
             + b.x * b.x + b.y * b.y + b.z * b.z + b.w * b.w;
    ss = waveReduceSum(ss);
    if (lane == 0) rmn[row] = 1.f / fmaxf(sqrtf(ss), 1e-12f);
  } else {
    const int idx = bid - 8448;
    const int r0 = (idx & 255) * 32, c0 = (idx >> 8) * 32;
    const int tr = threadIdx.x >> 5, tc = threadIdx.x & 31;
#pragma unroll
    for (int p = 0; p < 4; ++p)
      tile[tr + p * 8][tc] = vals[(size_t)(r0 + tr + p * 8) * HH + c0 + tc];
    __syncthreads();
#pragma unroll
    for (int p = 0; p < 4; ++p)
      vT[(size_t)(c0 + tr + p * 8) * DICT + r0 + tc] = __float2half(tile[tc][tr + p * 8]);
  }
}

// ---------------- main kernels ----------------
// fused preact GEMM + LSTM gates: weights are gate-interleaved so fragment
// fj == gate g for hidden unit u = 16*((n0>>6)+wc) + (lane&15).
__global__ __launch_bounds__(256) void k_preact(
    const __half* __restrict__ x_h, const __half* __restrict__ h_h,
    const __half* __restrict__ Wip, const __half* __restrict__ Whp,
    const float* __restrict__ bi, const float* __restrict__ bh,
    const float* __restrict__ c_prev,
    float* __restrict__ ct, float* __restrict__ ot, __half* __restrict__ ct_h) {
  __shared__ char smem[BM * BKT * 2 + 128 * BKT * 2] __attribute__((aligned(16)));
  const int tid = threadIdx.x;
  const int m0 = blockIdx.y * 128, n0 = blockIdx.x * 128;
  f32x4 acc[4][4]; zero_acc4(acc);
  gemm_seg<128, 4>(x_h, HH, Wip, HH, m0, n0, HH, smem, tid, acc);
  gemm_seg<128, 4>(h_h, HH, Whp, HH, m0, n0, HH, smem, tid, acc);
  const int lane = tid & 63, wid = tid >> 6, wr = wid >> 1, wc = wid & 1;
  const int r = lane & 15;
  const int u = ((n0 >> 6) + wc) * 16 + r;
  float bsum[4];
#pragma unroll
  for (int g = 0; g < 4; ++g) {
    int orig = g * 512 + u + (g == 3 ? 3 : 0);
    bsum[g] = bi[orig] + bh[orig];
  }
#pragma unroll
  for (int fi = 0; fi < 4; ++fi)
#pragma unroll
    for (int q = 0; q < 4; ++q) {
      int m = m0 + wr * 64 + fi * 16 + (lane >> 4) * 4 + q;
      float f  = sigmoidf_(acc[fi][0][q] + bsum[0]);
      float o  = sigmoidf_(acc[fi][1][q] + bsum[1]);
      float ii = sigmoidf_(acc[fi][2][q] + bsum[2]);
      float cn = tanhf(acc[fi][3][q] + bsum[3]);
      size_t off = (size_t)m * HH + u;
      float cc = c_prev[off] * f + ii * cn;
      ct[off] = cc; ot[off] = o; ct_h[off] = __float2half(cc);
    }
}

// exact fp32 LCA scalar gates (orig cols 1536..1538) + rqn from ct
__global__ __launch_bounds__(256) void k_scalars(
    const float* __restrict__ x, const float* __restrict__ h,
    const float* __restrict__ Wi, const float* __restrict__ Wh,
    const float* __restrict__ bi, const float* __restrict__ bh,
    const float* __restrict__ ct,
    float* __restrict__ inps, float* __restrict__ leak,
    float* __restrict__ comp, float* __restrict__ rqn) {
  const int b = blockIdx.x, wid = threadIdx.x >> 6, lane = threadIdx.x & 63;
  const int j = lane * 8;
  if (wid < 3) {
    const float* wi = Wi + (size_t)(1536 + wid) * HH + j;
    const float* wh = Wh + (size_t)(1536 + wid) * HH + j;
    const float* xr = x + (size_t)b * HH + j;
    const float* hr = h + (size_t)b * HH + j;
    float4 xa = *(const float4*)(xr), xb = *(const float4*)(xr + 4);
    float4 wa = *(const float4*)(wi), wb = *(const float4*)(wi + 4);
    float4 ha = *(const float4*)(hr), hb = *(const float4*)(hr + 4);
    float4 va = *(const float4*)(wh), vb = *(const float4*)(wh + 4);
    float s = xa.x * wa.x + xa.y * wa.y + xa.z * wa.z + xa.w * wa.w
            + xb.x * wb.x + xb.y * wb.y + xb.z * wb.z + xb.w * wb.w
            + ha.x * va.x + ha.y * va.y + ha.z * va.z + ha.w * va.w
            + hb.x * vb.x + hb.y * vb.y + hb.z * vb.z + hb.w * vb.w;
    s = waveReduceSum(s);
    if (lane == 0) {
      float v = sigmoidf_(s + bi[1536 + wid] + bh[1536 + wid]);
      if (wid == 0) inps[b] = v; else if (wid == 1) leak[b] = v; else comp[b] = v;
    }
  } else {
    const float* cr = ct + (size_t)b * HH + j;
    float4 a = *(const float4*)(cr), d = *(const float4*)(cr + 4);
    float ss = a.x * a.x + a.y * a.y + a.z * a.z + a.w * a.w
             + d.x * d.x + d.y * d.y + d.z * d.z + d.w * d.w;
    ss = waveReduceSum(ss);
    if (lane == 0) rqn[b] = 1.f / fmaxf(sqrtf(ss), 1e-12f);
  }
}

__global__ __launch_bounds__(256) void k_sim(
    const __half* __restrict__ ct_h, const __half* __restrict__ vals_h,
    const float* __restrict__ rqn, const float* __restrict__ rmn,
    __half* __restrict__ sim_h) {
  __shared__ char smem[BM * BKT * 2 + 128 * BKT * 2] __attribute__((aligned(16)));
  const int tid = threadIdx.x;
  const int m0 = blockIdx.y * 128, n0 = blockIdx.x * 128;
  f32x4 acc[4][4]; zero_acc4(acc);
  gemm_seg<128, 4>(ct_h, HH, vals_h, HH, m0, n0, HH, smem, tid, acc);
  const int lane = tid & 63, wid = tid >> 6, wr = wid >> 1, wc = wid & 1;
#pragma unroll
  for (int fi = 0; fi < 4; ++fi)
#pragma unroll
    for (int fj = 0; fj < 4; ++fj)
#pragma unroll
      for (int q = 0; q < 4; ++q) {
        int m = m0 + wr * 64 + fi * 16 + (lane >> 4) * 4 + q;
        int n = n0 + wc * 64 + fj * 16 + (lane & 15);
        sim_h[(size_t)m * DICT + n] = __float2half(acc[fi][fj][q] * rqn[m] * rmn[n]);
      }
}

// LCA: thread owns 32 CONTIGUOUS dict elems (64B vector loads/stores, f16)
__global__ __launch_bounds__(256) void k_lca(
    const __half* __restrict__ sim_h, const float* __restrict__ inps,
    const float* __restrict__ leak, const float* __restrict__ comp,
    __half* __restrict__ w_h) {
  const int b = blockIdx.x, t = threadIdx.x;
  const __half* srow = sim_h + (size_t)b * DICT + t * 32;
  const float ffs = DTT * inps[b];
  const float a   = 1.0f - DTT * leak[b] + DTT * comp[b];
  const float cdt = DTT * comp[b];
  float ff[32], V[32];
#pragma unroll
  for (int i = 0; i < 4; ++i) {
    f16x8 v8 = *(const f16x8*)(srow + i * 8);
#pragma unroll
    for (int j = 0; j < 8; ++j) { ff[i * 8 + j] = ffs * (float)v8[j]; V[i * 8 + j] = 0.f; }
  }
  __shared__ float ps[4];
  for (int it = 0; it < NCYC; ++it) {
    float s = 0.f;
#pragma unroll
    for (int i = 0; i < 32; ++i) s += V[i];
    s = waveReduceSum(s);
    if ((t & 63) == 0) ps[t >> 6] = s;
    __syncthreads();
    float S = ps[0] + ps[1] + ps[2] + ps[3];
    __syncthreads();
    float sub = cdt * S;
#pragma unroll
    for (int i = 0; i < 32; ++i) V[i] = fmaxf(fmaf(a, V[i], ff[i] - sub), 0.f);
  }
  __half* wrow = w_h + (size_t)b * DICT + t * 32;
#pragma unroll
  for (int i = 0; i < 4; ++i) {
    f16x8 o8;
#pragma unroll
    for (int j = 0; j < 8; ++j) o8[j] = (_Float16)V[i * 8 + j];
    *(f16x8*)(wrow + i * 8) = o8;
  }
}

// split-K partial GEMM; bid -> (m,n,s) XCD-bijective: each XCD owns one K-stripe
__global__ __launch_bounds__(256) void k_mt_p(
    const __half* __restrict__ w_h, const __half* __restrict__ vT_h,
    float* __restrict__ partial) {
  __shared__ char smem[BM * BKT * 2 + 64 * BKT * 2] __attribute__((aligned(16)));
  const int tid = threadIdx.x, bid = blockIdx.x;
  const int xcd = bid & 7, idx = bid >> 3;
  const int n = idx & 7, q = idx >> 3;
  const int g = (q << 3) | xcd;     // g = m*4 + s
  const int m = g >> 2, s = g & 3;
  const int m0 = m * 128, n0 = n * 64;
  f32x4 acc[4][2]; zero_acc2(acc);
  gemm_seg<64, 2>(w_h + s * 2048, DICT, vT_h + s * 2048, DICT, m0, n0, 2048, smem, tid, acc);
  const int lane = tid & 63, wid = tid >> 6, wr = wid >> 1, wc = wid & 1;
  float* pbase = partial + (size_t)s * (BATCH * HH);
#pragma unroll
  for (int fi = 0; fi < 4; ++fi)
#pragma unroll
    for (int fj = 0; fj < 2; ++fj)
#pragma unroll
      for (int qq = 0; qq < 4; ++qq) {
        int mm = m0 + wr * 64 + fi * 16 + (lane >> 4) * 4 + qq;
        int nn = n0 + wc * 32 + fj * 16 + (lane & 15);
        pbase[(size_t)mm * HH + nn] = acc[fi][fj][qq];
      }
}

// reduce 4 partials + full epilogue (cm, ht, nv scatter, ht_h)
__global__ __launch_bounds__(256) void k_mt_red(
    const float* __restrict__ partial,
    const float* __restrict__ ct, const float* __restrict__ ot, const int* __restrict__ mptr,
    float* __restrict__ out_mt, float* __restrict__ out_cmt, float* __restrict__ out_ht,
    float* __restrict__ out_nv, __half* __restrict__ ht_h) {
  const int i4 = blockIdx.x * 256 + threadIdx.x;
  const size_t off = (size_t)i4 * 4;
  const int m = i4 >> 7;
  float4 p  = *(const float4*)(partial + off);
  float4 p1 = *(const float4*)(partial + 2097152 + off);
  float4 p2 = *(const float4*)(partial + 4194304 + off);
  float4 p3 = *(const float4*)(partial + 6291456 + off);
  p.x += p1.x + p2.x + p3.x;
  p.y += p1.y + p2.y + p3.y;
  p.z += p1.z + p2.z + p3.z;
  p.w += p1.w + p2.w + p3.w;
  float4 c4 = *(const float4*)(ct + off);
  float4 o4 = *(const float4*)(ot + off);
  float4 cm, hv;
  cm.x = c4.x + p.x; hv.x = o4.x * tanhf(cm.x);
  cm.y = c4.y + p.y; hv.y = o4.y * tanhf(cm.y);
  cm.z = c4.z + p.z; hv.z = o4.z * tanhf(cm.z);
  cm.w = c4.w + p.w; hv.w = o4.w * tanhf(cm.w);
  *(float4*)(out_mt + off)  = p;
  *(float4*)(out_cmt + off) = cm;
  *(float4*)(out_ht + off)  = hv;
  *(__half2*)(ht_h + off)     = __floats2half2_rn(hv.x, hv.y);
  *(__half2*)(ht_h + off + 2) = __floats2half2_rn(hv.z, hv.w);
  const int nvrow = (mptr[0] + m) & (DICT - 1);
  *(float4*)(out_nv + (size_t)nvrow * HH + (off & 511)) = cm;
}

__global__ __launch_bounds__(256) void k_a2c(
    const __half* __restrict__ ht_h, const __half* __restrict__ Wih_h,
    const float* __restrict__ bih, float* __restrict__ a2c) {
  __shared__ char smem[BM * BKT * 2 + 64 * BKT * 2] __attribute__((aligned(16)));
  const int tid = threadIdx.x;
  const int bid = blockIdx.x;
  const int xn = (bid >> 3) & 7, ym = (bid & 7) | ((bid >> 6) << 3);
  const int m0 = ym * 128, n0 = xn * 64;
  f32x4 acc[4][2]; zero_acc2(acc);
  gemm_seg<64, 2>(ht_h, HH, Wih_h, HH, m0, n0, HH, smem, tid, acc);
  const int lane = tid & 63, wid = tid >> 6, wr = wid >> 1, wc = wid & 1;
#pragma unroll
  for (int fi = 0; fi < 4; ++fi)
#pragma unroll
    for (int fj = 0; fj < 2; ++fj)
#pragma unroll
      for (int q = 0; q < 4; ++q) {
        int m = m0 + wr * 64 + fi * 16 + (lane >> 4) * 4 + q;
        int n = n0 + wc * 32 + fj * 16 + (lane & 15);
        a2c[(size_t)m * HH + n] = fmaxf(acc[fi][fj][q] + bih[n], 0.f);
      }
}

__global__ __launch_bounds__(256) void k_actor(
    const float* __restrict__ a2c,
    const float* __restrict__ Wact, const float* __restrict__ bact,
    const float* __restrict__ Wcr, const float* __restrict__ bcr,
    float* __restrict__ out_pi, float* __restrict__ out_val) {
  const int b = blockIdx.x * 4 + (threadIdx.x >> 6);
  const int lane = threadIdx.x & 63;
  const float* hrow = a2c + (size_t)b * HH;
  float4 a0 = *(const float4*)(hrow + (lane << 3));
  float4 a1 = *(const float4*)(hrow + (lane << 3) + 4);
  float lg[17];
#pragma unroll
  for (int o = 0; o < 17; ++o) {
    const float* wr = (o < 16) ? (Wact + (size_t)o * HH) : Wcr;
    float4 w0 = *(const float4*)(wr + (lane << 3));
    float4 w1 = *(const float4*)(wr + (lane << 3) + 4);
    float s = a0.x * w0.x + a0.y * w0.y + a0.z * w0.z + a0.w * w0.w
            + a1.x * w1.x + a1.y * w1.y + a1.z * w1.z + a1.w * w1.w;
    lg[o] = waveReduceSum(s);
  }
#pragma unroll
  for (int o = 0; o < 16; ++o) lg[o] += bact[o];
  float mx = lg[0];
#pragma unroll
  for (int o = 1; o < 16; ++o) mx = fmaxf(mx, lg[o]);
  float e[16], sum = 0.f;
#pragma unroll
  for (int o = 0; o < 16; ++o) { e[o] = __expf(lg[o] - mx); sum += e[o]; }
  float rs = 1.f / sum;
  if (lane == 0) {
#pragma unroll
    for (int o = 0; o < 16; ++o) out_pi[(size_t)b * 16 + o] = e[o] * rs;
    out_val[b] = lg[16] + bcr[0];
  }
}

// ---------------- launch ----------------
extern "C" void kernel_launch(void* const* d_in, const int* in_sizes, int n_in,
                              void* d_out, int out_size, void* d_ws, size_t ws_size,
                              hipStream_t stream) {
  const float* x    = (const float*)d_in[0];
  const float* h    = (const float*)d_in[1];
  const float* c    = (const float*)d_in[2];
  const float* Wi   = (const float*)d_in[3];
  const float* bi   = (const float*)d_in[4];
  const float* Wh   = (const float*)d_in[5];
  const float* bh   = (const float*)d_in[6];
  const float* vals = (const float*)d_in[7];
  const float* Wih  = (const float*)d_in[8];
  const float* bih  = (const float*)d_in[9];
  const float* Wact = (const float*)d_in[10];
  const float* bact = (const float*)d_in[11];
  const float* Wcr  = (const float*)d_in[12];
  const float* bcr  = (const float*)d_in[13];
  const int*   mptr = (const int*)d_in[14];

  float* F = (float*)d_ws;
  // region P: w_h f16 (k_lca -> k_mt_p)
  __half* w_h    = (__half*)F;
  // region S: sim_h f16 (k_sim -> k_lca); after dead: a2c at start, partial at +16M f
  __half* sim_h   = (__half*)(F + 16777216);
  float*  a2c     = F + 16777216;
  float*  partial = F + 33554432;           // 8.4M floats
  float*  ct     = F + 50331648;            // 2,097,152
  float*  ot     = F + 52428800;            // 2,097,152
  __half* ct_h   = (__half*)(F + 54525952); // 1,048,576 f
  __half* vals_h = (__half*)(F + 55574528); // 2,097,152 f
  __half* vT_h   = (__half*)(F + 57671680); // 2,097,152 f
  __half* x_h    = (__half*)(F + 59768832); // 1,048,576 f (later reused as ht_h)
  __half* ht_h   = x_h;
  __half* h_h    = (__half*)(F + 60817408); // 1,048,576 f
  __half* Wip_h  = (__half*)(F + 61865984); // 524,288 f (2048x512 f16)
  __half* Whp_h  = (__half*)(F + 62423040); // 524,288 f
  __half* Wih_h  = (__half*)(F + 62980096); // 131,072 f
  float*  inps   = F + 63111168;
  float*  leak   = inps + 4096;
  float*  comp   = leak + 4096;
  float*  rqn    = comp + 4096;
  float*  rmn    = rqn + 4096;              // 8192

  float* out     = (float*)d_out;
  float* out_pi  = out;
  float* out_val = out + 65536;
  float* out_ht  = out + 69632;
  float* out_cmt = out_ht + 2097152;
  float* out_mt  = out_cmt + 2097152;
  float* out_nv  = out_mt + 2097152;

  dim3 b256(256);
  k_prep   <<<12544, b256, 0, stream>>>(x, h, Wi, Wh, Wih, vals,
                                        x_h, h_h, Wip_h, Whp_h, Wih_h,
                                        out_nv, vals_h, rmn, vT_h);
  k_preact <<<dim3(16, 32), b256, 0, stream>>>(x_h, h_h, Wip_h, Whp_h, bi, bh, c,
                                               ct, ot, ct_h);
  k_scalars<<<BATCH, b256, 0, stream>>>(x, h, Wi, Wh, bi, bh, ct, inps, leak, comp, rqn);
  k_sim    <<<dim3(64, 32), b256, 0, stream>>>(ct_h, vals_h, rqn, rmn, sim_h);
  k_lca    <<<BATCH, b256, 0, stream>>>(sim_h, inps, leak, comp, w_h);
  k_mt_p   <<<1024, b256, 0, stream>>>(w_h, vT_h, partial);
  k_mt_red <<<2048, b256, 0, stream>>>(partial, ct, ot, mptr,
                                       out_mt, out_cmt, out_ht, out_nv, ht_h);
  k_a2c    <<<256, b256, 0, stream>>>(ht_h, Wih_h, bih, a2c);
  k_actor  <<<BATCH / 4, b256, 0, stream>>>(a2c, Wact, bact, Wcr, bcr, out_pi, out_val);
}

// Round 6
// 218.663 us; speedup vs baseline: 6.2628x; 1.0134x over previous
//
#include <hip/hip_runtime.h>
#include <hip/hip_fp16.h>
#include <math.h>

#define HH    512
#define DICT  8192
#define BATCH 4096
#define NCYC  10
#define DTT   0.6f

#define BM  128
#define BKT 64    // K elements per tile; row = 128 bytes = 8 chunks of 16B

using f16x8 = __attribute__((ext_vector_type(8))) _Float16;
using f32x4 = __attribute__((ext_vector_type(4))) float;

__device__ __forceinline__ float sigmoidf_(float x) { return 1.0f / (1.0f + __expf(-x)); }

__device__ __forceinline__ float waveReduceSum(float v) {
#pragma unroll
  for (int o = 1; o < 64; o <<= 1) v += __shfl_xor(v, o);
  return v;
}

__device__ __forceinline__ void gld16(const void* g, void* l) {
  __builtin_amdgcn_global_load_lds(
      (const __attribute__((address_space(1))) void*)g,
      (__attribute__((address_space(3))) void*)l, 16, 0, 0);
}

template<int N> __device__ __forceinline__ void vmwait() {
  if constexpr (N == 8)      asm volatile("s_waitcnt vmcnt(8)" ::: "memory");
  else if constexpr (N == 6) asm volatile("s_waitcnt vmcnt(6)" ::: "memory");
  else                       asm volatile("s_waitcnt vmcnt(0)" ::: "memory");
  __builtin_amdgcn_sched_barrier(0);
}

__device__ __forceinline__ void blockbar() {
  asm volatile("" ::: "memory");
  __builtin_amdgcn_s_barrier();
  __builtin_amdgcn_sched_barrier(0);
}

// Stage ROWS x 64 f16 tile. LDS linear (global_load_lds rule), source pre-swizzled:
// data chunk k4 of row r lands in LDS slot (k4 ^ (r&7)).
template<int ROWS>
__device__ __forceinline__ void stage_tile(const __half* gbase, int ld, char* lds, int tid) {
  constexpr int ISS = ROWS * 8 / 256;
#pragma unroll
  for (int i = 0; i < ISS; ++i) {
    int cidx = i * 256 + tid;
    int row  = cidx >> 3;
    int slot = cidx & 7;
    int k4   = slot ^ (row & 7);
    gld16(gbase + (size_t)row * ld + k4 * 8, lds + cidx * 16);
  }
}

__device__ __forceinline__ f16x8 frag_ld(const char* lds, int row, int kchunk) {
  int slot = kchunk ^ (row & 7);
  return *(const f16x8*)(lds + row * 128 + slot * 16);
}

template<int FN>
__device__ __forceinline__ void tile_mfma(const char* As, const char* Bs,
                                          int lane, int wr, int wc, f32x4 (&acc)[4][FN]) {
  const int g = lane >> 4, r = lane & 15;
#pragma unroll
  for (int ks = 0; ks < 2; ++ks) {
    f16x8 af[4], bfr[FN];
#pragma unroll
    for (int i = 0; i < 4; ++i)
      af[i] = frag_ld(As, wr * 64 + i * 16 + r, ks * 4 + g);
#pragma unroll
    for (int j = 0; j < FN; ++j)
      bfr[j] = frag_ld(Bs, wc * (FN * 16) + j * 16 + r, ks * 4 + g);
#pragma unroll
    for (int i = 0; i < 4; ++i)
#pragma unroll
      for (int j = 0; j < FN; ++j)
        acc[i][j] = __builtin_amdgcn_mfma_f32_16x16x32_f16(af[i], bfr[j], acc[i][j], 0, 0, 0);
  }
}

// C[m,n] += sum_k A[m,k]*B[n,k], both f16 k-contiguous (NT).
// 2-phase pipeline with COUNTED vmcnt: issue next tile's global_load_lds,
// wait vmcnt(NL) (current tile landed, next tile's NL loads stay in flight),
// raw s_barrier (no drain), compute, barrier (WAR for re-stage).
template<int BN, int FN>
__device__ __forceinline__ void gemm_seg(const __half* A, int lda, const __half* B, int ldb,
                                         int m0, int n0, int K, char* lds, int tid,
                                         f32x4 (&acc)[4][FN]) {
  constexpr int ABYTES = BM * BKT * 2;
  constexpr int BBYTES = BN * BKT * 2;
  constexpr int BUF = ABYTES + BBYTES;
  constexpr int NL = (BM + BN) * 8 / 256;   // per-thread vmem instrs per stage
  const int lane = tid & 63, wid = tid >> 6;
  const int wr = wid >> 1, wc = wid & 1;
  const int nt = K / BKT;
  const __half* Ab = A + (size_t)m0 * lda;
  const __half* Bb = B + (size_t)n0 * ldb;
  stage_tile<BM>(Ab, lda, lds, tid);
  stage_tile<BN>(Bb, ldb, lds + ABYTES, tid);
  int cur = 0;
  for (int t = 0; t < nt; ++t) {
    char* curb = lds + cur * BUF;
    if (t + 1 < nt) {
      char* nxt = lds + (cur ^ 1) * BUF;
      stage_tile<BM>(Ab + (t + 1) * BKT, lda, nxt, tid);
      stage_tile<BN>(Bb + (t + 1) * BKT, ldb, nxt + ABYTES, tid);
      vmwait<NL>();
    } else {
      vmwait<0>();
    }
    blockbar();                 // tile t landed for all waves
    tile_mfma<FN>(curb, curb + ABYTES, lane, wr, wc, acc);
    blockbar();                 // all reads of curb done before next re-stage
    cur ^= 1;
  }
}

__device__ __forceinline__ void zero_acc4(f32x4 (&a)[4][4]) {
  f32x4 z = {0.f, 0.f, 0.f, 0.f};
#pragma unroll
  for (int i = 0; i < 4; ++i)
#pragma unroll
    for (int j = 0; j < 4; ++j) a[i][j] = z;
}
__device__ __forceinline__ void zero_acc2(f32x4 (&a)[4][2]) {
  f32x4 z = {0.f, 0.f, 0.f, 0.f};
#pragma unroll
  for (int i = 0; i < 4; ++i)
#pragma unroll
    for (int j = 0; j < 2; ++j) a[i][j] = z;
}

// ---------------- fused prep (cvt + vals + transpose in one launch) ----------------
__global__ __launch_bounds__(256) void k_prep(
    const float* __restrict__ x, const float* __restrict__ h,
    const float* __restrict__ Wi, const float* __restrict__ Wh, const float* __restrict__ Wih,
    const float* __restrict__ vals, const int* __restrict__ mptr,
    __half* __restrict__ x_h, __half* __restrict__ h_h,
    __half* __restrict__ Wip_h, __half* __restrict__ Whp_h, __half* __restrict__ Wih_h,
    float* __restrict__ nv, __half* __restrict__ vals_h, float* __restrict__ rmn,
    __half* __restrict__ vT) {
  __shared__ float tile[32][33];
  const int bid = blockIdx.x;
  if (bid < 6400) {
    int gq = bid * 256 + threadIdx.x;
    const float* src; __half* dst; int si, di;
    if (gq < 524288) {                    // x
      src = x; dst = x_h; si = di = gq * 4;
    } else if (gq < 1048576) {            // h
      src = h; dst = h_h; si = di = (gq - 524288) * 4;
    } else if (gq < 1310720) {            // Wi permuted gate-interleaved
      int iq = gq - 1048576;
      int jp = iq >> 7, k4 = (iq & 127) << 2;
      int U = jp >> 6, g = (jp >> 4) & 3, r = jp & 15;
      int u = U * 16 + r;
      int orig = g * 512 + u + (g == 3 ? 3 : 0);
      src = Wi; dst = Wip_h; si = orig * 512 + k4; di = jp * 512 + k4;
    } else if (gq < 1572864) {            // Wh permuted
      int iq = gq - 1310720;
      int jp = iq >> 7, k4 = (iq & 127) << 2;
      int U = jp >> 6, g = (jp >> 4) & 3, r = jp & 15;
      int u = U * 16 + r;
      int orig = g * 512 + u + (g == 3 ? 3 : 0);
      src = Wh; dst = Whp_h; si = orig * 512 + k4; di = jp * 512 + k4;
    } else if (gq < 1638400) {            // Wih
      int iq = gq - 1572864;
      src = Wih; dst = Wih_h; si = di = iq * 4;
    } else return;
    float4 v = *(const float4*)(src + si);
    *(__half2*)(dst + di)     = __floats2half2_rn(v.x, v.y);
    *(__half2*)(dst + di + 2) = __floats2half2_rn(v.z, v.w);
  } else if (bid < 8448) {
    const int row  = (bid - 6400) * 4 + (threadIdx.x >> 6);
    const int lane = threadIdx.x & 63;
    const float* vr = vals + (size_t)row * HH + lane * 8;
    float4 a = *(const float4*)(vr);
    float4 b = *(const float4*)(vr + 4);
    // skip nv copy for rows that k_mt_red will overwrite
    if (((row + DICT - mptr[0]) & (DICT - 1)) >= BATCH) {
      float* nvp = nv + (size_t)row * HH + lane * 8;
      *(float4*)(nvp)     = a;
      *(float4*)(nvp + 4) = b;
    }
    __half* vh = vals_h + (size_t)row * HH + lane * 8;
    *(__half2*)(vh)     = __floats2half2_rn(a.x, a.y);
    *(__half2*)(vh + 2) = __floats2half2_rn(a.z, a.w);
    *(__half2*)(vh + 4) = __floats2half2_rn(b.x, b.y);
    *(__half2*)(vh + 6) = __floats2half2_rn(b.z, b.w);
    float ss = a.x * a.x + a.y * a.y + a.z * a.z + a.w * a.w
             + b.x * b.x + b.y * b.y + b.z * b.z + b.w * b.w;
    ss = waveReduceSum(ss);
    if (lane == 0) rmn[row] = 1.f / fmaxf(sqrtf(ss), 1e-12f);
  } else {
    const int idx = bid - 8448;
    const int r0 = (idx & 255) * 32, c0 = (idx >> 8) * 32;
    const int tr = threadIdx.x >> 5, tc = threadIdx.x & 31;
#pragma unroll
    for (int p = 0; p < 4; ++p)
      tile[tr + p * 8][tc] = vals[(size_t)(r0 + tr + p * 8) * HH + c0 + tc];
    __syncthreads();
#pragma unroll
    for (int p = 0; p < 4; ++p)
      vT[(size_t)(c0 + tr + p * 8) * DICT + r0 + tc] = __float2half(tile[tc][tr + p * 8]);
  }
}

// ---------------- main kernels ----------------
// fused preact GEMM + LSTM gates (gate-interleaved weights: fragment fj == gate)
__global__ __launch_bounds__(256) void k_preact(
    const __half* __restrict__ x_h, const __half* __restrict__ h_h,
    const __half* __restrict__ Wip, const __half* __restrict__ Whp,
    const float* __restrict__ bi, const float* __restrict__ bh,
    const float* __restrict__ c_prev,
    float* __restrict__ ct, float* __restrict__ ot, __half* __restrict__ ct_h) {
  __shared__ char smem[2 * (BM * BKT * 2 + 128 * BKT * 2)] __attribute__((aligned(16)));
  const int tid = threadIdx.x;
  const int m0 = blockIdx.y * 128, n0 = blockIdx.x * 128;
  f32x4 acc[4][4]; zero_acc4(acc);
  gemm_seg<128, 4>(x_h, HH, Wip, HH, m0, n0, HH, smem, tid, acc);
  gemm_seg<128, 4>(h_h, HH, Whp, HH, m0, n0, HH, smem, tid, acc);
  const int lane = tid & 63, wid = tid >> 6, wr = wid >> 1, wc = wid & 1;
  const int r = lane & 15;
  const int u = ((n0 >> 6) + wc) * 16 + r;
  float bsum[4];
#pragma unroll
  for (int g = 0; g < 4; ++g) {
    int orig = g * 512 + u + (g == 3 ? 3 : 0);
    bsum[g] = bi[orig] + bh[orig];
  }
#pragma unroll
  for (int fi = 0; fi < 4; ++fi)
#pragma unroll
    for (int q = 0; q < 4; ++q) {
      int m = m0 + wr * 64 + fi * 16 + (lane >> 4) * 4 + q;
      float f  = sigmoidf_(acc[fi][0][q] + bsum[0]);
      float o  = sigmoidf_(acc[fi][1][q] + bsum[1]);
      float ii = sigmoidf_(acc[fi][2][q] + bsum[2]);
      float cn = tanhf(acc[fi][3][q] + bsum[3]);
      size_t off = (size_t)m * HH + u;
      float cc = c_prev[off] * f + ii * cn;
      ct[off] = cc; ot[off] = o; ct_h[off] = __float2half(cc);
    }
}

// exact fp32 LCA scalar gates (orig cols 1536..1538) + rqn from ct
__global__ __launch_bounds__(256) void k_scalars(
    const float* __restrict__ x, const float* __restrict__ h,
    const float* __restrict__ Wi, const float* __restrict__ Wh,
    const float* __restrict__ bi, const float* __restrict__ bh,
    const float* __restrict__ ct,
    float* __restrict__ inps, float* __restrict__ leak,
    float* __restrict__ comp, float* __restrict__ rqn) {
  const int b = blockIdx.x, wid = threadIdx.x >> 6, lane = threadIdx.x & 63;
  const int j = lane * 8;
  if (wid < 3) {
    const float* wi = Wi + (size_t)(1536 + wid) * HH + j;
    const float* wh = Wh + (size_t)(1536 + wid) * HH + j;
    const float* xr = x + (size_t)b * HH + j;
    const float* hr = h + (size_t)b * HH + j;
    float4 xa = *(const float4*)(xr), xb = *(const float4*)(xr + 4);
    float4 wa = *(const float4*)(wi), wb = *(const float4*)(wi + 4);
    float4 ha = *(const float4*)(hr), hb = *(const float4*)(hr + 4);
    float4 va = *(const float4*)(wh), vb = *(const float4*)(wh + 4);
    float s = xa.x * wa.x + xa.y * wa.y + xa.z * wa.z + xa.w * wa.w
            + xb.x * wb.x + xb.y * wb.y + xb.z * wb.z + xb.w * wb.w
            + ha.x * va.x + ha.y * va.y + ha.z * va.z + ha.w * va.w
            + hb.x * vb.x + hb.y * vb.y + hb.z * vb.z + hb.w * vb.w;
    s = waveReduceSum(s);
    if (lane == 0) {
      float v = sigmoidf_(s + bi[1536 + wid] + bh[1536 + wid]);
      if (wid == 0) inps[b] = v; else if (wid == 1) leak[b] = v; else comp[b] = v;
    }
  } else {
    const float* cr = ct + (size_t)b * HH + j;
    float4 a = *(const float4*)(cr), d = *(const float4*)(cr + 4);
    float ss = a.x * a.x + a.y * a.y + a.z * a.z + a.w * a.w
             + d.x * d.x + d.y * d.y + d.z * d.z + d.w * d.w;
    ss = waveReduceSum(ss);
    if (lane == 0) rqn[b] = 1.f / fmaxf(sqrtf(ss), 1e-12f);
  }
}

__global__ __launch_bounds__(256) void k_sim(
    const __half* __restrict__ ct_h, const __half* __restrict__ vals_h,
    const float* __restrict__ rqn, const float* __restrict__ rmn,
    __half* __restrict__ sim_h) {
  __shared__ char smem[2 * (BM * BKT * 2 + 128 * BKT * 2)] __attribute__((aligned(16)));
  const int tid = threadIdx.x;
  const int m0 = blockIdx.y * 128, n0 = blockIdx.x * 128;
  f32x4 acc[4][4]; zero_acc4(acc);
  gemm_seg<128, 4>(ct_h, HH, vals_h, HH, m0, n0, HH, smem, tid, acc);
  const int lane = tid & 63, wid = tid >> 6, wr = wid >> 1, wc = wid & 1;
  // epilogue via LDS transpose: vectorized f16x8 row stores
  float* T = (float*)smem;
  const int g = lane >> 4, r = lane & 15;
  const int lrow = tid >> 3, c16 = (tid & 7) * 16;
  const int nR = n0 + c16;
  float rmv[16];
  *(float4*)(rmv)      = *(const float4*)(rmn + nR);
  *(float4*)(rmv + 4)  = *(const float4*)(rmn + nR + 4);
  *(float4*)(rmv + 8)  = *(const float4*)(rmn + nR + 8);
  *(float4*)(rmv + 12) = *(const float4*)(rmn + nR + 12);
#pragma unroll
  for (int fi = 0; fi < 4; ++fi) {
    if (fi) __syncthreads();
#pragma unroll
    for (int fj = 0; fj < 4; ++fj)
#pragma unroll
      for (int q = 0; q < 4; ++q)
        T[(wr * 16 + g * 4 + q) * 132 + wc * 64 + fj * 16 + r] = acc[fi][fj][q];
    __syncthreads();
    int m = m0 + (lrow >> 4) * 64 + fi * 16 + (lrow & 15);
    float rq = rqn[m];
    const float* Tr = T + lrow * 132 + c16;
    f16x8 o0, o1;
#pragma unroll
    for (int j = 0; j < 8; ++j) o0[j] = (_Float16)(Tr[j] * rq * rmv[j]);
#pragma unroll
    for (int j = 0; j < 8; ++j) o1[j] = (_Float16)(Tr[8 + j] * rq * rmv[8 + j]);
    *(f16x8*)(sim_h + (size_t)m * DICT + nR)     = o0;
    *(f16x8*)(sim_h + (size_t)m * DICT + nR + 8) = o1;
  }
}

// LCA: thread owns 32 CONTIGUOUS dict elems (64B vector loads/stores, f16)
__global__ __launch_bounds__(256) void k_lca(
    const __half* __restrict__ sim_h, const float* __restrict__ inps,
    const float* __restrict__ leak, const float* __restrict__ comp,
    __half* __restrict__ w_h) {
  const int b = blockIdx.x, t = threadIdx.x;
  const __half* srow = sim_h + (size_t)b * DICT + t * 32;
  const float ffs = DTT * inps[b];
  const float a   = 1.0f - DTT * leak[b] + DTT * comp[b];
  const float cdt = DTT * comp[b];
  float ff[32], V[32];
#pragma unroll
  for (int i = 0; i < 4; ++i) {
    f16x8 v8 = *(const f16x8*)(srow + i * 8);
#pragma unroll
    for (int j = 0; j < 8; ++j) { ff[i * 8 + j] = ffs * (float)v8[j]; V[i * 8 + j] = 0.f; }
  }
  __shared__ float ps[4];
  for (int it = 0; it < NCYC; ++it) {
    float s = 0.f;
#pragma unroll
    for (int i = 0; i < 32; ++i) s += V[i];
    s = waveReduceSum(s);
    if ((t & 63) == 0) ps[t >> 6] = s;
    __syncthreads();
    float S = ps[0] + ps[1] + ps[2] + ps[3];
    __syncthreads();
    float sub = cdt * S;
#pragma unroll
    for (int i = 0; i < 32; ++i) V[i] = fmaxf(fmaf(a, V[i], ff[i] - sub), 0.f);
  }
  __half* wrow = w_h + (size_t)b * DICT + t * 32;
#pragma unroll
  for (int i = 0; i < 4; ++i) {
    f16x8 o8;
#pragma unroll
    for (int j = 0; j < 8; ++j) o8[j] = (_Float16)V[i * 8 + j];
    *(f16x8*)(wrow + i * 8) = o8;
  }
}

// split-K partial GEMM; bid -> (m,n,s) XCD-bijective: each XCD owns one K-stripe
__global__ __launch_bounds__(256) void k_mt_p(
    const __half* __restrict__ w_h, const __half* __restrict__ vT_h,
    float* __restrict__ partial) {
  __shared__ char smem[2 * (BM * BKT * 2 + 64 * BKT * 2)] __attribute__((aligned(16)));
  const int tid = threadIdx.x, bid = blockIdx.x;
  const int xcd = bid & 7, idx = bid >> 3;
  const int n = idx & 7, q = idx >> 3;
  const int g = (q << 3) | xcd;     // g = m*4 + s
  const int m = g >> 2, s = g & 3;
  const int m0 = m * 128, n0 = n * 64;
  f32x4 acc[4][2]; zero_acc2(acc);
  gemm_seg<64, 2>(w_h + s * 2048, DICT, vT_h + s * 2048, DICT, m0, n0, 2048, smem, tid, acc);
  const int lane = tid & 63, wid = tid >> 6, wr = wid >> 1, wc = wid & 1;
  float* pbase = partial + (size_t)s * (BATCH * HH);
  float* T = (float*)smem;
  const int gg = lane >> 4, r = lane & 15;
  const int lrow = tid >> 3, c8 = (tid & 7) * 8;
#pragma unroll
  for (int fi = 0; fi < 4; ++fi) {
    if (fi) __syncthreads();
#pragma unroll
    for (int fj = 0; fj < 2; ++fj)
#pragma unroll
      for (int qq = 0; qq < 4; ++qq)
        T[(wr * 16 + gg * 4 + qq) * 68 + wc * 32 + fj * 16 + r] = acc[fi][fj][qq];
    __syncthreads();
    int mm = m0 + (lrow >> 4) * 64 + fi * 16 + (lrow & 15);
    float* dst = pbase + (size_t)mm * HH + n0 + c8;
    *(float4*)dst       = *(const float4*)(T + lrow * 68 + c8);
    *(float4*)(dst + 4) = *(const float4*)(T + lrow * 68 + c8 + 4);
  }
}

// reduce 4 partials + full epilogue (cm, ht, nv scatter, ht_h)
__global__ __launch_bounds__(256) void k_mt_red(
    const float* __restrict__ partial,
    const float* __restrict__ ct, const float* __restrict__ ot, const int* __restrict__ mptr,
    float* __restrict__ out_mt, float* __restrict__ out_cmt, float* __restrict__ out_ht,
    float* __restrict__ out_nv, __half* __restrict__ ht_h) {
  const int i4 = blockIdx.x * 256 + threadIdx.x;
  const size_t off = (size_t)i4 * 4;
  const int m = i4 >> 7;
  float4 p  = *(const float4*)(partial + off);
  float4 p1 = *(const float4*)(partial + 2097152 + off);
  float4 p2 = *(const float4*)(partial + 4194304 + off);
  float4 p3 = *(const float4*)(partial + 6291456 + off);
  p.x += p1.x + p2.x + p3.x;
  p.y += p1.y + p2.y + p3.y;
  p.z += p1.z + p2.z + p3.z;
  p.w += p1.w + p2.w + p3.w;
  float4 c4 = *(const float4*)(ct + off);
  float4 o4 = *(const float4*)(ot + off);
  float4 cm, hv;
  cm.x = c4.x + p.x; hv.x = o4.x * tanhf(cm.x);
  cm.y = c4.y + p.y; hv.y = o4.y * tanhf(cm.y);
  cm.z = c4.z + p.z; hv.z = o4.z * tanhf(cm.z);
  cm.w = c4.w + p.w; hv.w = o4.w * tanhf(cm.w);
  *(float4*)(out_mt + off)  = p;
  *(float4*)(out_cmt + off) = cm;
  *(float4*)(out_ht + off)  = hv;
  *(__half2*)(ht_h + off)     = __floats2half2_rn(hv.x, hv.y);
  *(__half2*)(ht_h + off + 2) = __floats2half2_rn(hv.z, hv.w);
  const int nvrow = (mptr[0] + m) & (DICT - 1);
  *(float4*)(out_nv + (size_t)nvrow * HH + (off & 511)) = cm;
}

__global__ __launch_bounds__(256) void k_a2c(
    const __half* __restrict__ ht_h, const __half* __restrict__ Wih_h,
    const float* __restrict__ bih, float* __restrict__ a2c) {
  __shared__ char smem[2 * (BM * BKT * 2 + 64 * BKT * 2)] __attribute__((aligned(16)));
  const int tid = threadIdx.x;
  const int bid = blockIdx.x;
  const int xn = (bid >> 3) & 7, ym = (bid & 7) | ((bid >> 6) << 3);
  const int m0 = ym * 128, n0 = xn * 64;
  f32x4 acc[4][2]; zero_acc2(acc);
  gemm_seg<64, 2>(ht_h, HH, Wih_h, HH, m0, n0, HH, smem, tid, acc);
  const int lane = tid & 63, wid = tid >> 6, wr = wid >> 1, wc = wid & 1;
  float* T = (float*)smem;
  const int gg = lane >> 4, r = lane & 15;
  const int lrow = tid >> 3, c8 = (tid & 7) * 8;
  float4 b0 = *(const float4*)(bih + n0 + c8);
  float4 b1 = *(const float4*)(bih + n0 + c8 + 4);
#pragma unroll
  for (int fi = 0; fi < 4; ++fi) {
    if (fi) __syncthreads();
#pragma unroll
    for (int fj = 0; fj < 2; ++fj)
#pragma unroll
      for (int qq = 0; qq < 4; ++qq)
        T[(wr * 16 + gg * 4 + qq) * 68 + wc * 32 + fj * 16 + r] = acc[fi][fj][qq];
    __syncthreads();
    int mm = m0 + (lrow >> 4) * 64 + fi * 16 + (lrow & 15);
    float4 v0 = *(const float4*)(T + lrow * 68 + c8);
    float4 v1 = *(const float4*)(T + lrow * 68 + c8 + 4);
    v0.x = fmaxf(v0.x + b0.x, 0.f); v0.y = fmaxf(v0.y + b0.y, 0.f);
    v0.z = fmaxf(v0.z + b0.z, 0.f); v0.w = fmaxf(v0.w + b0.w, 0.f);
    v1.x = fmaxf(v1.x + b1.x, 0.f); v1.y = fmaxf(v1.y + b1.y, 0.f);
    v1.z = fmaxf(v1.z + b1.z, 0.f); v1.w = fmaxf(v1.w + b1.w, 0.f);
    float* dst = a2c + (size_t)mm * HH + n0 + c8;
    *(float4*)dst       = v0;
    *(float4*)(dst + 4) = v1;
  }
}

__global__ __launch_bounds__(256) void k_actor(
    const float* __restrict__ a2c,
    const float* __restrict__ Wact, const float* __restrict__ bact,
    const float* __restrict__ Wcr, const float* __restrict__ bcr,
    float* __restrict__ out_pi, float* __restrict__ out_val) {
  const int b = blockIdx.x * 4 + (threadIdx.x >> 6);
  const int lane = threadIdx.x & 63;
  const float* hrow = a2c + (size_t)b * HH;
  float4 a0 = *(const float4*)(hrow + (lane << 3));
  float4 a1 = *(const float4*)(hrow + (lane << 3) + 4);
  float lg[17];
#pragma unroll
  for (int o = 0; o < 17; ++o) {
    const float* wr = (o < 16) ? (Wact + (size_t)o * HH) : Wcr;
    float4 w0 = *(const float4*)(wr + (lane << 3));
    float4 w1 = *(const float4*)(wr + (lane << 3) + 4);
    float s = a0.x * w0.x + a0.y * w0.y + a0.z * w0.z + a0.w * w0.w
            + a1.x * w1.x + a1.y * w1.y + a1.z * w1.z + a1.w * w1.w;
    lg[o] = waveReduceSum(s);
  }
#pragma unroll
  for (int o = 0; o < 16; ++o) lg[o] += bact[o];
  float mx = lg[0];
#pragma unroll
  for (int o = 1; o < 16; ++o) mx = fmaxf(mx, lg[o]);
  float e[16], sum = 0.f;
#pragma unroll
  for (int o = 0; o < 16; ++o) { e[o] = __expf(lg[o] - mx); sum += e[o]; }
  float rs = 1.f / sum;
  if (lane == 0) {
#pragma unroll
    for (int o = 0; o < 16; ++o) out_pi[(size_t)b * 16 + o] = e[o] * rs;
    out_val[b] = lg[16] + bcr[0];
  }
}

// ---------------- launch ----------------
extern "C" void kernel_launch(void* const* d_in, const int* in_sizes, int n_in,
                              void* d_out, int out_size, void* d_ws, size_t ws_size,
                              hipStream_t stream) {
  const float* x    = (const float*)d_in[0];
  const float* h    = (const float*)d_in[1];
  const float* c    = (const float*)d_in[2];
  const float* Wi   = (const float*)d_in[3];
  const float* bi   = (const float*)d_in[4];
  const float* Wh   = (const float*)d_in[5];
  const float* bh   = (const float*)d_in[6];
  const float* vals = (const float*)d_in[7];
  const float* Wih  = (const float*)d_in[8];
  const float* bih  = (const float*)d_in[9];
  const float* Wact = (const float*)d_in[10];
  const float* bact = (const float*)d_in[11];
  const float* Wcr  = (const float*)d_in[12];
  const float* bcr  = (const float*)d_in[13];
  const int*   mptr = (const int*)d_in[14];

  float* F = (float*)d_ws;
  __half* w_h    = (__half*)F;              // region P: w_h f16 (k_lca -> k_mt_p)
  __half* sim_h   = (__half*)(F + 16777216);// region S: sim_h f16, then a2c/partial
  float*  a2c     = F + 16777216;
  float*  partial = F + 33554432;           // 8.4M floats
  float*  ct     = F + 50331648;            // 2,097,152
  float*  ot     = F + 52428800;            // 2,097,152
  __half* ct_h   = (__half*)(F + 54525952); // 1,048,576 f
  __half* vals_h = (__half*)(F + 55574528); // 2,097,152 f
  __half* vT_h   = (__half*)(F + 57671680); // 2,097,152 f
  __half* x_h    = (__half*)(F + 59768832); // 1,048,576 f (later reused as ht_h)
  __half* ht_h   = x_h;
  __half* h_h    = (__half*)(F + 60817408); // 1,048,576 f
  __half* Wip_h  = (__half*)(F + 61865984); // 524,288 f (2048x512 f16)
  __half* Whp_h  = (__half*)(F + 62423040); // 524,288 f
  __half* Wih_h  = (__half*)(F + 62980096); // 131,072 f
  float*  inps   = F + 63111168;
  float*  leak   = inps + 4096;
  float*  comp   = leak + 4096;
  float*  rqn    = comp + 4096;
  float*  rmn    = rqn + 4096;              // 8192

  float* out     = (float*)d_out;
  float* out_pi  = out;
  float* out_val = out + 65536;
  float* out_ht  = out + 69632;
  float* out_cmt = out_ht + 2097152;
  float* out_mt  = out_cmt + 2097152;
  float* out_nv  = out_mt + 2097152;

  dim3 b256(256);
  k_prep   <<<12544, b256, 0, stream>>>(x, h, Wi, Wh, Wih, vals, mptr,
                                        x_h, h_h, Wip_h, Whp_h, Wih_h,
                                        out_nv, vals_h, rmn, vT_h);
  k_preact <<<dim3(16, 32), b256, 0, stream>>>(x_h, h_h, Wip_h, Whp_h, bi, bh, c,
                                               ct, ot, ct_h);
  k_scalars<<<BATCH, b256, 0, stream>>>(x, h, Wi, Wh, bi, bh, ct, inps, leak, comp, rqn);
  k_sim    <<<dim3(64, 32), b256, 0, stream>>>(ct_h, vals_h, rqn, rmn, sim_h);
  k_lca    <<<BATCH, b256, 0, stream>>>(sim_h, inps, leak, comp, w_h);
  k_mt_p   <<<1024, b256, 0, stream>>>(w_h, vT_h, partial);
  k_mt_red <<<2048, b256, 0, stream>>>(partial, ct, ot, mptr,
                                       out_mt, out_cmt, out_ht, out_nv, ht_h);
  k_a2c    <<<256, b256, 0, stream>>>(ht_h, Wih_h, bih, a2c);
  k_actor  <<<BATCH / 4, b256, 0, stream>>>(a2c, Wact, bact, Wcr, bcr, out_pi, out_val);
}